// Round 1
// baseline (1898.719 us; speedup 1.0000x reference)
//
#include <hip/hip_runtime.h>

typedef _Float16 f16;
typedef __attribute__((ext_vector_type(8))) _Float16 f16x8;
typedef __attribute__((ext_vector_type(4))) _Float16 f16x4;
typedef __attribute__((ext_vector_type(4))) float f32x4;

// Problem constants
// B=2 S=2048 D=2048 H=16 KVH=4 HD=128 E=8 TOPK=2 F=1024, T=B*S=4096

// ---------------------------------------------------------------- utilities

__global__ __launch_bounds__(256) void cvt_f16(const float* __restrict__ in,
                                               f16* __restrict__ outp, int n4) {
  int i = blockIdx.x * 256 + threadIdx.x;
  if (i >= n4) return;
  float4 v = ((const float4*)in)[i];
  f16x4 o;
  o[0] = (f16)v.x; o[1] = (f16)v.y; o[2] = (f16)v.z; o[3] = (f16)v.w;
  ((f16x4*)outp)[i] = o;
}

__global__ __launch_bounds__(256) void rope_tables(float* __restrict__ cost,
                                                   float* __restrict__ sint) {
  int i = blockIdx.x * 256 + threadIdx.x;
  if (i >= 2048 * 64) return;
  int s = i >> 6, j = i & 63;
  float invf = powf(10000.f, -(float)j * (1.f / 64.f));
  float ang = (float)s * invf;
  cost[i] = cosf(ang);
  sint[i] = sinf(ang);
}

// x[t][2048] -> f16 rmsnorm output
__global__ __launch_bounds__(256) void rmsnorm_f16(const float* __restrict__ X,
                                                   const float* __restrict__ w,
                                                   f16* __restrict__ outp) {
  int t = blockIdx.x, tid = threadIdx.x;
  const float* row = X + (long)t * 2048;
  float4 v0 = ((const float4*)row)[tid];
  float4 v1 = ((const float4*)row)[tid + 256];
  float ss = v0.x * v0.x + v0.y * v0.y + v0.z * v0.z + v0.w * v0.w +
             v1.x * v1.x + v1.y * v1.y + v1.z * v1.z + v1.w * v1.w;
  for (int o = 32; o; o >>= 1) ss += __shfl_xor(ss, o);
  __shared__ float red[4];
  if ((tid & 63) == 0) red[tid >> 6] = ss;
  __syncthreads();
  ss = red[0] + red[1] + red[2] + red[3];
  float inv = rsqrtf(ss * (1.f / 2048.f) + 1e-6f);
  float4 w0 = ((const float4*)w)[tid];
  float4 w1 = ((const float4*)w)[tid + 256];
  f16x4 a, b;
  a[0] = (f16)(v0.x * inv * w0.x); a[1] = (f16)(v0.y * inv * w0.y);
  a[2] = (f16)(v0.z * inv * w0.z); a[3] = (f16)(v0.w * inv * w0.w);
  b[0] = (f16)(v1.x * inv * w1.x); b[1] = (f16)(v1.y * inv * w1.y);
  b[2] = (f16)(v1.z * inv * w1.z); b[3] = (f16)(v1.w * inv * w1.w);
  f16x4* orow = (f16x4*)(outp + (long)t * 2048);
  orow[tid] = a;
  orow[tid + 256] = b;
}

// ---------------------------------------------------------------- NT GEMM
// C[row][n] = sum_k A[arow][k] * W[n][k]  (+Res), MFMA 16x16x32 f16.
// 128x128 tile, 4 waves each 64x64 (4x4 MFMA tiles), BK=32.
// MoE mode: eoff/ecnt give per-expert row window; gather maps slot->token row.
__global__ __launch_bounds__(256) void gemm_nt(
    const f16* __restrict__ A, const f16* __restrict__ W0,
    float* __restrict__ C, const float* __restrict__ Res,
    const int* __restrict__ gather, const int* __restrict__ eoff,
    const int* __restrict__ ecnt, int M, int N, int K, long wstride) {
  int e = blockIdx.z;
  int row0 = 0, nrows = M;
  if (eoff) { row0 = eoff[e]; nrows = ecnt[e]; }
  int mt = blockIdx.x;
  if (mt * 128 >= nrows) return;
  int nt = blockIdx.y;
  const f16* W = W0 + (long)e * wstride;

  __shared__ __align__(16) f16 As[128 * 32];
  __shared__ __align__(16) f16 Bs[128 * 32];

  int tid = threadIdx.x;
  int lane = tid & 63, wid = tid >> 6;
  int quad = lane >> 4, l15 = lane & 15;
  int wm = wid & 1, wn = wid >> 1;

  // staging rows are k-invariant: precompute
  long arow[2]; int brow[2];
  for (int r = 0; r < 2; r++) {
    int rowi = r * 64 + (tid >> 2);
    int lr = mt * 128 + rowi;
    int g = (lr < nrows) ? (row0 + lr) : row0;
    arow[r] = gather ? gather[g] : g;
    brow[r] = nt * 128 + rowi;
  }
  int kc8 = (tid & 3) * 8;

  f32x4 acc[4][4] = {};
  for (int k0 = 0; k0 < K; k0 += 32) {
    f16x8 va[2], vb[2];
    for (int r = 0; r < 2; r++) {
      va[r] = *(const f16x8*)(A + arow[r] * K + k0 + kc8);
      vb[r] = *(const f16x8*)(W + (long)brow[r] * K + k0 + kc8);
    }
    __syncthreads();
    for (int r = 0; r < 2; r++) {
      int rowi = r * 64 + (tid >> 2);
      *(f16x8*)&As[rowi * 32 + kc8] = va[r];
      *(f16x8*)&Bs[rowi * 32 + kc8] = vb[r];
    }
    __syncthreads();
    f16x8 a[4], b[4];
    for (int i = 0; i < 4; i++)
      a[i] = *(const f16x8*)&As[(wm * 64 + i * 16 + l15) * 32 + quad * 8];
    for (int j = 0; j < 4; j++)
      b[j] = *(const f16x8*)&Bs[(wn * 64 + j * 16 + l15) * 32 + quad * 8];
    for (int i = 0; i < 4; i++)
      for (int j = 0; j < 4; j++)
        acc[i][j] = __builtin_amdgcn_mfma_f32_16x16x32_f16(a[i], b[j], acc[i][j], 0, 0, 0);
  }
  // epilogue: C/D layout row=(lane>>4)*4+reg, col=lane&15  [m89/m91 verified]
  for (int i = 0; i < 4; i++) {
    int lrb = mt * 128 + wm * 64 + i * 16 + quad * 4;
    for (int rr = 0; rr < 4; rr++) {
      int lr = lrb + rr;
      if (lr >= nrows) continue;
      long orow = row0 + lr;
      for (int j = 0; j < 4; j++) {
        int col = nt * 128 + wn * 64 + j * 16 + l15;
        float v = acc[i][j][rr];
        if (Res) v += Res[orow * N + col];
        C[orow * N + col] = v;
      }
    }
  }
}

// ------------------------------------------------- q/k per-head norm + rope
// X: [t][nh*128] fp32; out: [b][nh][s][128] f16 (scaled by `scale` after rope)
__global__ __launch_bounds__(128) void qknorm_rope(
    const float* __restrict__ X, const float* __restrict__ wn,
    const float* __restrict__ cost, const float* __restrict__ sint,
    f16* __restrict__ outp, int nh, float scale) {
  int idx = blockIdx.x;
  int t = idx / nh, h = idx - t * nh;
  int b = t >> 11, s = t & 2047;
  int d = threadIdx.x;
  float v = X[(long)t * nh * 128 + h * 128 + d];
  float ss = v * v;
  for (int o = 32; o; o >>= 1) ss += __shfl_xor(ss, o);
  __shared__ float red[2];
  __shared__ float tmp[128];
  if ((d & 63) == 0) red[d >> 6] = ss;
  __syncthreads();
  ss = red[0] + red[1];
  float inv = rsqrtf(ss * (1.f / 128.f) + 1e-6f);
  float vn = v * inv * wn[d];
  tmp[d] = vn;
  __syncthreads();
  float res;
  if (d < 64) {
    float c = cost[s * 64 + d], sn = sint[s * 64 + d];
    res = vn * c - tmp[d + 64] * sn;
  } else {
    float c = cost[s * 64 + d - 64], sn = sint[s * 64 + d - 64];
    res = tmp[d - 64] * sn + vn * c;
  }
  outp[((long)(b * nh + h) * 2048 + s) * 128 + d] = (f16)(res * scale);
}

// v fp32 [t][kvh*128] -> f16 [b][kvh][s][128]
__global__ __launch_bounds__(256) void vcvt_kernel(const float* __restrict__ Vf,
                                                   f16* __restrict__ vh) {
  int i = blockIdx.x * 256 + threadIdx.x;  // T*512
  int d = i & 127;
  int rest = i >> 7;
  int kv = rest & 3;
  int t = rest >> 2;
  int b = t >> 11, s = t & 2047;
  vh[((long)(b * 4 + kv) * 2048 + s) * 128 + d] = (f16)Vf[i];
}

// ---------------------------------------------------------- flash attention
// Q pre-scaled by 1/sqrt(HD). Block: 64 q rows (4 waves x 16), K-tiles of 32.
__global__ __launch_bounds__(256) void attn_kernel(
    const f16* __restrict__ Q, const f16* __restrict__ Kb,
    const f16* __restrict__ Vb, f16* __restrict__ O) {
  int qt = blockIdx.x;
  int bh = blockIdx.y;
  int b = bh >> 4, h = bh & 15;
  int kvh = h >> 2;
  int q0 = qt * 64;
  int tid = threadIdx.x, lane = tid & 63, wid = tid >> 6;
  int quad = lane >> 4, l15 = lane & 15;

  const f16* Qb = Q + ((long)(b * 16 + h) * 2048 + q0 + wid * 16) * 128;
  f16x8 qfr[4];
  for (int c = 0; c < 4; c++)
    qfr[c] = *(const f16x8*)(Qb + (long)l15 * 128 + c * 32 + quad * 8);

  const f16* Kg = Kb + (long)(b * 4 + kvh) * 2048 * 128;
  const f16* Vg = Vb + (long)(b * 4 + kvh) * 2048 * 128;

  __shared__ __align__(16) f16 Ks[32 * 128];
  __shared__ __align__(16) f16 Vt[128 * 32];
  __shared__ __align__(16) f16 Ps[4][16 * 32];

  f32x4 oacc[8] = {};
  float mi[4], li[4];
  int qrow[4];
  for (int r = 0; r < 4; r++) {
    mi[r] = -__builtin_inff();
    li[r] = 0.f;
    qrow[r] = q0 + wid * 16 + quad * 4 + r;
  }

  int ktiles = (q0 + 64) >> 5;
  for (int kt = 0; kt < ktiles; kt++) {
    int k0 = kt * 32;
    __syncthreads();
    for (int r = 0; r < 2; r++) {
      int c = r * 256 + tid;
      int krow = c >> 4, dc = c & 15;
      f16x8 kv = *(const f16x8*)(Kg + (long)(k0 + krow) * 128 + dc * 8);
      *(f16x8*)&Ks[krow * 128 + dc * 8] = kv;
      f16x8 vv = *(const f16x8*)(Vg + (long)(k0 + krow) * 128 + dc * 8);
      for (int j = 0; j < 8; j++) Vt[(dc * 8 + j) * 32 + krow] = vv[j];
    }
    __syncthreads();
    // scores: two 16(q)x16(k) tiles
    f32x4 sc[2] = {};
    for (int hf = 0; hf < 2; hf++)
      for (int c = 0; c < 4; c++) {
        f16x8 kf = *(const f16x8*)&Ks[(hf * 16 + l15) * 128 + c * 32 + quad * 8];
        sc[hf] = __builtin_amdgcn_mfma_f32_16x16x32_f16(qfr[c], kf, sc[hf], 0, 0, 0);
      }
    // causal mask + online softmax (rows = quad*4+r, col = l15)
    f32x4 p[2];
    float alpha[4];
    for (int r = 0; r < 4; r++) {
      for (int hf = 0; hf < 2; hf++) {
        int colk = k0 + hf * 16 + l15;
        if (colk > qrow[r]) sc[hf][r] = -__builtin_inff();
      }
      float mx = fmaxf(sc[0][r], sc[1][r]);
      for (int o = 8; o; o >>= 1) mx = fmaxf(mx, __shfl_xor(mx, o));
      float mnew = fmaxf(mi[r], mx);  // finite after tile 0 (col 0 always valid)
      alpha[r] = expf(mi[r] - mnew);
      mi[r] = mnew;
      float s = 0.f;
      for (int hf = 0; hf < 2; hf++) {
        float pv = expf(sc[hf][r] - mnew);
        p[hf][r] = pv;
        s += pv;
      }
      for (int o = 8; o; o >>= 1) s += __shfl_xor(s, o);
      li[r] = li[r] * alpha[r] + s;
    }
    for (int n = 0; n < 8; n++)
      for (int r = 0; r < 4; r++) oacc[n][r] *= alpha[r];
    // P: C-layout -> A-layout via LDS (wave-private)
    for (int hf = 0; hf < 2; hf++)
      for (int r = 0; r < 4; r++)
        Ps[wid][(quad * 4 + r) * 32 + hf * 16 + l15] = (f16)p[hf][r];
    __syncthreads();
    f16x8 pa = *(const f16x8*)&Ps[wid][l15 * 32 + quad * 8];
    for (int n = 0; n < 8; n++) {
      f16x8 vf = *(const f16x8*)&Vt[(n * 16 + l15) * 32 + quad * 8];
      oacc[n] = __builtin_amdgcn_mfma_f32_16x16x32_f16(pa, vf, oacc[n], 0, 0, 0);
    }
  }
  // O: [b][s][h][128]
  for (int r = 0; r < 4; r++) {
    float inv = 1.f / li[r];
    long base = (long)(b * 2048 + qrow[r]) * 2048 + h * 128;
    for (int n = 0; n < 8; n++)
      O[base + n * 16 + l15] = (f16)(oacc[n][r] * inv);
  }
}

// ---------------------------------------------------------------- routing
__global__ void zero8(int* p) { if (threadIdx.x < 8) p[threadIdx.x] = 0; }

// fp32 rmsnorm + router logits + top-2 (pure fp32 to match reference selection)
__global__ __launch_bounds__(256) void router_kernel(
    const float* __restrict__ X2, const float* __restrict__ wfn,
    const float* __restrict__ wr, int* __restrict__ route,
    int* __restrict__ toke, float* __restrict__ tokw) {
  int t = blockIdx.x, tid = threadIdx.x;
  const float* row = X2 + (long)t * 2048;
  float xv[8];
  float ss = 0.f;
  for (int j = 0; j < 8; j++) {
    float v = row[tid + j * 256];
    xv[j] = v;
    ss += v * v;
  }
  for (int o = 32; o; o >>= 1) ss += __shfl_xor(ss, o);
  __shared__ float red[4];
  int lane = tid & 63, wid = tid >> 6;
  if (lane == 0) red[wid] = ss;
  __syncthreads();
  ss = red[0] + red[1] + red[2] + red[3];
  float inv = rsqrtf(ss * (1.f / 2048.f) + 1e-6f);
  float xw[8];
  for (int j = 0; j < 8; j++) xw[j] = xv[j] * wfn[tid + j * 256];
  float lg[8];
  for (int e = 0; e < 8; e++) {
    float a = 0.f;
    for (int j = 0; j < 8; j++) a += xw[j] * wr[e * 2048 + tid + j * 256];
    for (int o = 32; o; o >>= 1) a += __shfl_xor(a, o);
    lg[e] = a;
  }
  __shared__ float lred[4][8];
  if (lane == 0)
    for (int e = 0; e < 8; e++) lred[wid][e] = lg[e];
  __syncthreads();
  if (tid == 0) {
    float l[8];
    for (int e = 0; e < 8; e++)
      l[e] = (lred[0][e] + lred[1][e] + lred[2][e] + lred[3][e]) * inv;
    int i0 = 0; float b0 = l[0];
    for (int e = 1; e < 8; e++) if (l[e] > b0) { b0 = l[e]; i0 = e; }
    int i1 = -1; float b1 = -__builtin_inff();
    for (int e = 0; e < 8; e++) {
      if (e == i0) continue;
      if (l[e] > b1) { b1 = l[e]; i1 = e; }
    }
    float w0 = 1.f / (1.f + expf(b1 - b0));  // normalized top-2 softmax
    toke[t * 2] = i0; toke[t * 2 + 1] = i1;
    tokw[t * 2] = w0; tokw[t * 2 + 1] = 1.f - w0;
    atomicAdd(&route[i0], 1);
    atomicAdd(&route[i1], 1);
  }
}

// route: [0..7]=counts [8..15]=fill [16..23]=offsets
__global__ void prefix_kernel(int* route) {
  if (threadIdx.x == 0) {
    int o = 0;
    for (int e = 0; e < 8; e++) { route[16 + e] = o; o += route[e]; }
  }
  if (threadIdx.x < 8) route[8 + threadIdx.x] = 0;
}

__global__ __launch_bounds__(256) void scatter_kernel(
    const int* __restrict__ toke, const float* __restrict__ tokw,
    int* __restrict__ route, int* __restrict__ tokc,
    float* __restrict__ gatew, int* __restrict__ tslots) {
  int t = blockIdx.x * 256 + threadIdx.x;
  if (t >= 4096) return;
  for (int j = 0; j < 2; j++) {
    int e = toke[t * 2 + j];
    int p = atomicAdd(&route[8 + e], 1);
    int slot = route[16 + e] + p;
    tokc[slot] = t;
    gatew[slot] = tokw[t * 2 + j];
    tslots[t * 2 + j] = slot;
  }
}

// act = gate_weight * silu(g) * u  (fp16 for down GEMM)
__global__ __launch_bounds__(256) void moe_act(const float* __restrict__ g,
                                               const float* __restrict__ u,
                                               const float* __restrict__ gatew,
                                               f16* __restrict__ act) {
  int i = blockIdx.x * 256 + threadIdx.x;  // 8192*1024
  int slot = i >> 10;
  float gv = g[i], uv = u[i];
  float sig = 1.f / (1.f + expf(-gv));
  act[i] = (f16)(gatew[slot] * gv * sig * uv);
}

// out += eo[slot0] + eo[slot1]   (deterministic 2-slot gather, no atomics)
__global__ __launch_bounds__(256) void final_add(float* __restrict__ outp,
                                                 const float* __restrict__ eo,
                                                 const int* __restrict__ tslots) {
  int i = blockIdx.x * 256 + threadIdx.x;  // T*2048
  int t = i >> 11, d = i & 2047;
  int s0 = tslots[t * 2], s1 = tslots[t * 2 + 1];
  outp[i] += eo[(long)s0 * 2048 + d] + eo[(long)s1 * 2048 + d];
}

// ---------------------------------------------------------------- launcher

extern "C" void kernel_launch(void* const* d_in, const int* in_sizes, int n_in,
                              void* d_out, int out_size, void* d_ws, size_t ws_size,
                              hipStream_t stream) {
  const float* x   = (const float*)d_in[0];
  const float* wan = (const float*)d_in[1];
  const float* wq  = (const float*)d_in[2];
  const float* wk  = (const float*)d_in[3];
  const float* wvp = (const float*)d_in[4];
  const float* wqn = (const float*)d_in[5];
  const float* wkn = (const float*)d_in[6];
  const float* wo  = (const float*)d_in[7];
  const float* wfn = (const float*)d_in[8];
  const float* wr  = (const float*)d_in[9];
  const float* wg  = (const float*)d_in[10];
  const float* wu  = (const float*)d_in[11];
  const float* wd  = (const float*)d_in[12];
  float* out = (float*)d_out;
  char* ws = (char*)d_ws;

  size_t off = 0;
  auto alloc = [&](size_t b) { size_t r = off; off += (b + 255) & ~(size_t)255; return r; };
  // lifetimes annotated; aliased regions share storage (total ~249 MB)
  size_t o_qf  = alloc((size_t)4096 * 2048 * 4);   // qkv-q fp32 | later: gate fp32
  size_t o_kf  = alloc((size_t)4096 * 512 * 4);    // k fp32
  size_t o_vf  = alloc((size_t)4096 * 512 * 4);    // v fp32
  size_t o_r3  = alloc((size_t)41943040);          // q/k/v/o f16 | later: up fp32
  size_t o_h   = alloc((size_t)4096 * 2048 * 2);   // h f16 | later: act f16
  size_t o_h2  = alloc((size_t)4096 * 2048 * 2);   // h2 f16
  size_t o_wqh = alloc((size_t)2048 * 2048 * 2);
  size_t o_wkh = alloc((size_t)512 * 2048 * 2);
  size_t o_wvh = alloc((size_t)512 * 2048 * 2);
  size_t o_woh = alloc((size_t)2048 * 2048 * 2);
  size_t o_r10 = alloc((size_t)2 * 8 * 1024 * 2048 * 2);  // wg+wu f16 | later: eo fp32
  size_t o_wdh = alloc((size_t)8 * 2048 * 1024 * 2);
  size_t o_cos = alloc((size_t)2048 * 64 * 4);
  size_t o_sin = alloc((size_t)2048 * 64 * 4);
  size_t o_rt  = alloc(256);
  size_t o_toke = alloc(4096 * 2 * 4);
  size_t o_tokw = alloc(4096 * 2 * 4);
  size_t o_tokc = alloc(4096 * 2 * 4);
  size_t o_gw   = alloc(4096 * 2 * 4);
  size_t o_ts   = alloc(4096 * 2 * 4);
  (void)ws_size; (void)in_sizes; (void)n_in; (void)out_size;

  float* qf = (float*)(ws + o_qf);
  float* gf = qf;
  float* kf = (float*)(ws + o_kf);
  float* vf = (float*)(ws + o_vf);
  f16* qh = (f16*)(ws + o_r3);
  f16* kh = (f16*)(ws + o_r3 + 16777216);
  f16* vh = (f16*)(ws + o_r3 + 20971520);
  f16* oh = (f16*)(ws + o_r3 + 25165824);
  float* uf = (float*)(ws + o_r3);
  f16* h16 = (f16*)(ws + o_h);
  f16* act16 = (f16*)(ws + o_h);
  f16* h2h = (f16*)(ws + o_h2);
  f16* wqh = (f16*)(ws + o_wqh);
  f16* wkh = (f16*)(ws + o_wkh);
  f16* wvh = (f16*)(ws + o_wvh);
  f16* woh = (f16*)(ws + o_woh);
  f16* wgh = (f16*)(ws + o_r10);
  f16* wuh = (f16*)(ws + o_r10 + 33554432);
  float* eo = (float*)(ws + o_r10);
  f16* wdh = (f16*)(ws + o_wdh);
  float* cost = (float*)(ws + o_cos);
  float* sint = (float*)(ws + o_sin);
  int* route = (int*)(ws + o_rt);
  int* toke = (int*)(ws + o_toke);
  float* tokw = (float*)(ws + o_tokw);
  int* tokc = (int*)(ws + o_tokc);
  float* gatew = (float*)(ws + o_gw);
  int* tslots = (int*)(ws + o_ts);

  // weights -> fp16
  cvt_f16<<<4096, 256, 0, stream>>>(wq, wqh, 1048576);
  cvt_f16<<<1024, 256, 0, stream>>>(wk, wkh, 262144);
  cvt_f16<<<1024, 256, 0, stream>>>(wvp, wvh, 262144);
  cvt_f16<<<4096, 256, 0, stream>>>(wo, woh, 1048576);
  cvt_f16<<<16384, 256, 0, stream>>>(wg, wgh, 4194304);
  cvt_f16<<<16384, 256, 0, stream>>>(wu, wuh, 4194304);
  cvt_f16<<<16384, 256, 0, stream>>>(wd, wdh, 4194304);
  rope_tables<<<512, 256, 0, stream>>>(cost, sint);

  // attention block
  rmsnorm_f16<<<4096, 256, 0, stream>>>(x, wan, h16);
  gemm_nt<<<dim3(32, 16, 1), 256, 0, stream>>>(h16, wqh, qf, nullptr, nullptr, nullptr, nullptr, 4096, 2048, 2048, 0);
  gemm_nt<<<dim3(32, 4, 1), 256, 0, stream>>>(h16, wkh, kf, nullptr, nullptr, nullptr, nullptr, 4096, 512, 2048, 0);
  gemm_nt<<<dim3(32, 4, 1), 256, 0, stream>>>(h16, wvh, vf, nullptr, nullptr, nullptr, nullptr, 4096, 512, 2048, 0);
  qknorm_rope<<<65536, 128, 0, stream>>>(qf, wqn, cost, sint, qh, 16, 0.08838834764831845f);
  qknorm_rope<<<16384, 128, 0, stream>>>(kf, wkn, cost, sint, kh, 4, 1.0f);
  vcvt_kernel<<<8192, 256, 0, stream>>>(vf, vh);
  attn_kernel<<<dim3(32, 32, 1), 256, 0, stream>>>(qh, kh, vh, oh);
  gemm_nt<<<dim3(32, 16, 1), 256, 0, stream>>>(oh, woh, out, x, nullptr, nullptr, nullptr, 4096, 2048, 2048, 0);

  // MoE block
  rmsnorm_f16<<<4096, 256, 0, stream>>>(out, wfn, h2h);
  zero8<<<1, 64, 0, stream>>>(route);
  router_kernel<<<4096, 256, 0, stream>>>(out, wfn, wr, route, toke, tokw);
  prefix_kernel<<<1, 64, 0, stream>>>(route);
  scatter_kernel<<<16, 256, 0, stream>>>(toke, tokw, route, tokc, gatew, tslots);
  gemm_nt<<<dim3(32, 8, 8), 256, 0, stream>>>(h2h, wgh, gf, nullptr, tokc, route + 16, route, 4096, 1024, 2048, 2097152);
  gemm_nt<<<dim3(32, 8, 8), 256, 0, stream>>>(h2h, wuh, uf, nullptr, tokc, route + 16, route, 4096, 1024, 2048, 2097152);
  moe_act<<<32768, 256, 0, stream>>>(gf, uf, gatew, act16);
  gemm_nt<<<dim3(32, 16, 8), 256, 0, stream>>>(act16, wdh, eo, nullptr, nullptr, route + 16, route, 4096, 2048, 1024, 2097152);
  final_add<<<32768, 256, 0, stream>>>(out, eo, tslots);
}

// Round 2
// 1791.956 us; speedup vs baseline: 1.0596x; 1.0596x over previous
//
#include <hip/hip_runtime.h>

typedef _Float16 f16;
typedef __attribute__((ext_vector_type(8))) _Float16 f16x8;
typedef __attribute__((ext_vector_type(4))) _Float16 f16x4;
typedef __attribute__((ext_vector_type(4))) float f32x4;

// B=2 S=2048 D=2048 H=16 KVH=4 HD=128 E=8 TOPK=2 F=1024, T=B*S=4096

#define GLD_LDS(gp, lp) \
  __builtin_amdgcn_global_load_lds((__attribute__((address_space(1))) void*)(gp), \
                                   (__attribute__((address_space(3))) void*)(lp), 16, 0, 0)

// ---------------------------------------------------------------- utilities

__global__ __launch_bounds__(256) void cvt_f16(const float* __restrict__ in,
                                               f16* __restrict__ outp, int n4) {
  int i = blockIdx.x * 256 + threadIdx.x;
  if (i >= n4) return;
  float4 v = ((const float4*)in)[i];
  f16x4 o;
  o[0] = (f16)v.x; o[1] = (f16)v.y; o[2] = (f16)v.z; o[3] = (f16)v.w;
  ((f16x4*)outp)[i] = o;
}

__global__ __launch_bounds__(256) void rope_tables(float* __restrict__ cost,
                                                   float* __restrict__ sint) {
  int i = blockIdx.x * 256 + threadIdx.x;
  if (i >= 2048 * 64) return;
  int s = i >> 6, j = i & 63;
  float invf = powf(10000.f, -(float)j * (1.f / 64.f));
  float ang = (float)s * invf;
  cost[i] = cosf(ang);
  sint[i] = sinf(ang);
}

// x[t][2048] -> f16 rmsnorm output
__global__ __launch_bounds__(256) void rmsnorm_f16(const float* __restrict__ X,
                                                   const float* __restrict__ w,
                                                   f16* __restrict__ outp) {
  int t = blockIdx.x, tid = threadIdx.x;
  const float* row = X + (long)t * 2048;
  float4 v0 = ((const float4*)row)[tid];
  float4 v1 = ((const float4*)row)[tid + 256];
  float ss = v0.x * v0.x + v0.y * v0.y + v0.z * v0.z + v0.w * v0.w +
             v1.x * v1.x + v1.y * v1.y + v1.z * v1.z + v1.w * v1.w;
  for (int o = 32; o; o >>= 1) ss += __shfl_xor(ss, o);
  __shared__ float red[4];
  if ((tid & 63) == 0) red[tid >> 6] = ss;
  __syncthreads();
  ss = red[0] + red[1] + red[2] + red[3];
  float inv = rsqrtf(ss * (1.f / 2048.f) + 1e-6f);
  float4 w0 = ((const float4*)w)[tid];
  float4 w1 = ((const float4*)w)[tid + 256];
  f16x4 a, b;
  a[0] = (f16)(v0.x * inv * w0.x); a[1] = (f16)(v0.y * inv * w0.y);
  a[2] = (f16)(v0.z * inv * w0.z); a[3] = (f16)(v0.w * inv * w0.w);
  b[0] = (f16)(v1.x * inv * w1.x); b[1] = (f16)(v1.y * inv * w1.y);
  b[2] = (f16)(v1.z * inv * w1.z); b[3] = (f16)(v1.w * inv * w1.w);
  f16x4* orow = (f16x4*)(outp + (long)t * 2048);
  orow[tid] = a;
  orow[tid + 256] = b;
}

// ---------------------------------------------------------------- NT GEMM
// C[row][n] = sum_k A[arow][k] * W[n][k]  (+Res), MFMA 16x16x32 f16.
// 128x128 tile, 4 waves each 64x64 (4x4 MFMA tiles), BK=32, m97-style
// global_load_lds staging. Ct non-null: write f16 transposed [b*N+col][2048].
__global__ __launch_bounds__(256) void gemm_nt(
    const f16* __restrict__ A, const f16* __restrict__ W0,
    float* __restrict__ C, const float* __restrict__ Res, f16* __restrict__ Ct,
    const int* __restrict__ gather, const int* __restrict__ eoff,
    const int* __restrict__ ecnt, int M, int N, int K, long wstride) {
  int e = blockIdx.z;
  int row0 = 0, nrows = M;
  if (eoff) { row0 = eoff[e]; nrows = ecnt[e]; }
  int mt = blockIdx.x;
  if (mt * 128 >= nrows) return;
  int nt = blockIdx.y;
  const f16* W = W0 + (long)e * wstride;

  __shared__ __align__(16) f16 As[128 * 32];
  __shared__ __align__(16) f16 Bs[128 * 32];

  int tid = threadIdx.x;
  int lane = tid & 63, wid = tid >> 6;
  int quad = lane >> 4, l15 = lane & 15;
  int wm = wid & 1, wn = wid >> 1;

  long arow[2]; int brow[2]; int rowi[2];
  for (int r = 0; r < 2; r++) {
    rowi[r] = r * 64 + (tid >> 2);
    int lr = mt * 128 + rowi[r];
    int g = (lr < nrows) ? (row0 + lr) : row0;
    arow[r] = gather ? gather[g] : g;
    brow[r] = nt * 128 + rowi[r];
  }
  int kc8 = (tid & 3) * 8;

  f32x4 acc[4][4] = {};
  for (int k0 = 0; k0 < K; k0 += 32) {
    __syncthreads();
    for (int r = 0; r < 2; r++) {
      GLD_LDS(A + arow[r] * K + k0 + kc8, &As[rowi[r] * 32 + kc8]);
      GLD_LDS(W + (long)brow[r] * K + k0 + kc8, &Bs[rowi[r] * 32 + kc8]);
    }
    __syncthreads();
    f16x8 a[4], b[4];
    for (int i = 0; i < 4; i++)
      a[i] = *(const f16x8*)&As[(wm * 64 + i * 16 + l15) * 32 + quad * 8];
    for (int j = 0; j < 4; j++)
      b[j] = *(const f16x8*)&Bs[(wn * 64 + j * 16 + l15) * 32 + quad * 8];
    for (int i = 0; i < 4; i++)
      for (int j = 0; j < 4; j++)
        acc[i][j] = __builtin_amdgcn_mfma_f32_16x16x32_f16(a[i], b[j], acc[i][j], 0, 0, 0);
  }
  // epilogue: C/D layout row=(lane>>4)*4+reg, col=lane&15  [m89/m91 verified]
  for (int i = 0; i < 4; i++) {
    int lrb = mt * 128 + wm * 64 + i * 16 + quad * 4;
    for (int rr = 0; rr < 4; rr++) {
      int lr = lrb + rr;
      if (lr >= nrows) continue;
      long orow = row0 + lr;
      if (Ct) {  // transposed f16 out: [b][col][s], b=orow>>11 s=orow&2047
        int bb = (int)(orow >> 11), s2 = (int)(orow & 2047);
        for (int j = 0; j < 4; j++) {
          int col = nt * 128 + wn * 64 + j * 16 + l15;
          Ct[((long)(bb * N + col)) * 2048 + s2] = (f16)acc[i][j][rr];
        }
      } else {
        for (int j = 0; j < 4; j++) {
          int col = nt * 128 + wn * 64 + j * 16 + l15;
          float v = acc[i][j][rr];
          if (Res) v += Res[orow * N + col];
          C[orow * N + col] = v;
        }
      }
    }
  }
}

// ------------------------------------------------- q/k per-head norm + rope
__global__ __launch_bounds__(128) void qknorm_rope(
    const float* __restrict__ X, const float* __restrict__ wn,
    const float* __restrict__ cost, const float* __restrict__ sint,
    f16* __restrict__ outp, int nh, float scale) {
  int idx = blockIdx.x;
  int t = idx / nh, h = idx - t * nh;
  int b = t >> 11, s = t & 2047;
  int d = threadIdx.x;
  float v = X[(long)t * nh * 128 + h * 128 + d];
  float ss = v * v;
  for (int o = 32; o; o >>= 1) ss += __shfl_xor(ss, o);
  __shared__ float red[2];
  __shared__ float tmp[128];
  if ((d & 63) == 0) red[d >> 6] = ss;
  __syncthreads();
  ss = red[0] + red[1];
  float inv = rsqrtf(ss * (1.f / 128.f) + 1e-6f);
  float vn = v * inv * wn[d];
  tmp[d] = vn;
  __syncthreads();
  float res;
  if (d < 64) {
    float c = cost[s * 64 + d], sn = sint[s * 64 + d];
    res = vn * c - tmp[d + 64] * sn;
  } else {
    float c = cost[s * 64 + d - 64], sn = sint[s * 64 + d - 64];
    res = tmp[d - 64] * sn + vn * c;
  }
  outp[((long)(b * nh + h) * 2048 + s) * 128 + d] = (f16)(res * scale);
}

// ---------------------------------------------------------- flash attention
// Q pre-scaled by 1/sqrt(HD). BQ=128 (4 waves x 32 q-rows), BK=64.
// K: [b][kvh][s][128] f16. V: TRANSPOSED [b][kvh][d][s] f16 (from V-GEMM).
// All LDS strides padded (K:136 V:72 P:76) -> <=2-way bank aliasing.
__global__ __launch_bounds__(256) void attn_kernel(
    const f16* __restrict__ Q, const f16* __restrict__ Kb,
    const f16* __restrict__ Vtg, f16* __restrict__ O) {
  int qt = 15 - blockIdx.x;  // heavy causal blocks dispatch first
  int bh = blockIdx.y;
  int b = bh >> 4, h = bh & 15;
  int kvh = h >> 2;
  int q0 = qt * 128;
  int tid = threadIdx.x, lane = tid & 63, wid = tid >> 6;
  int quad = lane >> 4, l15 = lane & 15;
  int qbase = q0 + wid * 32;

  const f16* Qb = Q + ((long)(b * 16 + h) * 2048 + qbase) * 128;
  f16x8 qfr[2][4];
  for (int m = 0; m < 2; m++)
    for (int c = 0; c < 4; c++)
      qfr[m][c] = *(const f16x8*)(Qb + (long)(m * 16 + l15) * 128 + c * 32 + quad * 8);

  const f16* Kg = Kb + (long)(b * 4 + kvh) * 2048 * 128;
  const f16* Vg = Vtg + (long)(b * 4 + kvh) * 128 * 2048;

  const int KSTR = 136, VSTR = 72, PSTR = 76;
  __shared__ __align__(16) f16 Ks[64 * 136];
  __shared__ __align__(16) f16 Vs[128 * 72];
  __shared__ __align__(16) f16 Ps[4][32 * 76];

  f32x4 oacc[2][8] = {};
  float mi[2][4], li[2][4];
  for (int m = 0; m < 2; m++)
    for (int r = 0; r < 4; r++) { mi[m][r] = -__builtin_inff(); li[m][r] = 0.f; }

  int niter = 2 * qt + 2;
  for (int kt = 0; kt < niter; kt++) {
    int k0 = kt * 64;
    __syncthreads();
    for (int rr = 0; rr < 4; rr++) {
      int idx = rr * 256 + tid;
      int krow = idx >> 4, dc8 = (idx & 15) * 8;
      *(f16x8*)&Ks[krow * KSTR + dc8] = *(const f16x8*)(Kg + (long)(k0 + krow) * 128 + dc8);
      int vd = idx >> 3, kc8 = (idx & 7) * 8;
      *(f16x8*)&Vs[vd * VSTR + kc8] = *(const f16x8*)(Vg + (long)vd * 2048 + k0 + kc8);
    }
    __syncthreads();
    // scores: 2 m-tiles x 4 k-subtiles, K=128 over d
    f32x4 sc[2][4] = {};
    for (int hf = 0; hf < 4; hf++)
      for (int c = 0; c < 4; c++) {
        f16x8 kf = *(const f16x8*)&Ks[(hf * 16 + l15) * KSTR + c * 32 + quad * 8];
        for (int m = 0; m < 2; m++)
          sc[m][hf] = __builtin_amdgcn_mfma_f32_16x16x32_f16(qfr[m][c], kf, sc[m][hf], 0, 0, 0);
      }
    bool diag = (k0 + 64 > q0);
    float p[2][4][4];
    for (int m = 0; m < 2; m++) {
      int rowb = qbase + m * 16 + quad * 4;
      for (int r = 0; r < 4; r++) {
        if (diag) {
          int row = rowb + r;
          for (int hf = 0; hf < 4; hf++)
            if (k0 + hf * 16 + l15 > row) sc[m][hf][r] = -__builtin_inff();
        }
        float mx = fmaxf(fmaxf(sc[m][0][r], sc[m][1][r]),
                         fmaxf(sc[m][2][r], sc[m][3][r]));
        for (int o = 8; o; o >>= 1) mx = fmaxf(mx, __shfl_xor(mx, o));
        float mnew = fmaxf(mi[m][r], mx);  // finite from kt=0 (col 0 valid)
        float al = exp2f((mi[m][r] - mnew) * 1.44269504f);
        mi[m][r] = mnew;
        float s = 0.f;
        for (int hf = 0; hf < 4; hf++) {
          float pv = exp2f((sc[m][hf][r] - mnew) * 1.44269504f);
          p[m][hf][r] = pv;
          s += pv;
        }
        for (int o = 8; o; o >>= 1) s += __shfl_xor(s, o);
        li[m][r] = li[m][r] * al + s;
        for (int n = 0; n < 8; n++) oacc[m][n][r] *= al;
      }
    }
    // P: C-layout -> A-layout via wave-private LDS (no barrier needed)
    for (int m = 0; m < 2; m++)
      for (int hf = 0; hf < 4; hf++)
        for (int r = 0; r < 4; r++)
          Ps[wid][(m * 16 + quad * 4 + r) * PSTR + hf * 16 + l15] = (f16)p[m][hf][r];
    for (int c = 0; c < 2; c++) {
      f16x8 pa[2];
      for (int m = 0; m < 2; m++)
        pa[m] = *(const f16x8*)&Ps[wid][(m * 16 + l15) * PSTR + c * 32 + quad * 8];
      for (int n = 0; n < 8; n++) {
        f16x8 vf = *(const f16x8*)&Vs[(n * 16 + l15) * VSTR + c * 32 + quad * 8];
        for (int m = 0; m < 2; m++)
          oacc[m][n] = __builtin_amdgcn_mfma_f32_16x16x32_f16(pa[m], vf, oacc[m][n], 0, 0, 0);
      }
    }
  }
  // O: [b][s][h][128] f16
  for (int m = 0; m < 2; m++)
    for (int r = 0; r < 4; r++) {
      int row = qbase + m * 16 + quad * 4 + r;
      float inv = 1.f / li[m][r];
      long basep = ((long)(b * 2048 + row)) * 2048 + h * 128;
      for (int n = 0; n < 8; n++)
        O[basep + n * 16 + l15] = (f16)(oacc[m][n][r] * inv);
    }
}

// ---------------------------------------------------------------- routing
__global__ void zero8(int* p) { if (threadIdx.x < 8) p[threadIdx.x] = 0; }

__global__ __launch_bounds__(256) void router_kernel(
    const float* __restrict__ X2, const float* __restrict__ wfn,
    const float* __restrict__ wr, int* __restrict__ route,
    int* __restrict__ toke, float* __restrict__ tokw) {
  int t = blockIdx.x, tid = threadIdx.x;
  const float* row = X2 + (long)t * 2048;
  float xv[8];
  float ss = 0.f;
  for (int j = 0; j < 8; j++) {
    float v = row[tid + j * 256];
    xv[j] = v;
    ss += v * v;
  }
  for (int o = 32; o; o >>= 1) ss += __shfl_xor(ss, o);
  __shared__ float red[4];
  int lane = tid & 63, wid = tid >> 6;
  if (lane == 0) red[wid] = ss;
  __syncthreads();
  ss = red[0] + red[1] + red[2] + red[3];
  float inv = rsqrtf(ss * (1.f / 2048.f) + 1e-6f);
  float xw[8];
  for (int j = 0; j < 8; j++) xw[j] = xv[j] * wfn[tid + j * 256];
  float lg[8];
  for (int e = 0; e < 8; e++) {
    float a = 0.f;
    for (int j = 0; j < 8; j++) a += xw[j] * wr[e * 2048 + tid + j * 256];
    for (int o = 32; o; o >>= 1) a += __shfl_xor(a, o);
    lg[e] = a;
  }
  __shared__ float lred[4][8];
  if (lane == 0)
    for (int e = 0; e < 8; e++) lred[wid][e] = lg[e];
  __syncthreads();
  if (tid == 0) {
    float l[8];
    for (int e = 0; e < 8; e++)
      l[e] = (lred[0][e] + lred[1][e] + lred[2][e] + lred[3][e]) * inv;
    int i0 = 0; float b0 = l[0];
    for (int e = 1; e < 8; e++) if (l[e] > b0) { b0 = l[e]; i0 = e; }
    int i1 = -1; float b1 = -__builtin_inff();
    for (int e = 0; e < 8; e++) {
      if (e == i0) continue;
      if (l[e] > b1) { b1 = l[e]; i1 = e; }
    }
    float w0 = 1.f / (1.f + expf(b1 - b0));
    toke[t * 2] = i0; toke[t * 2 + 1] = i1;
    tokw[t * 2] = w0; tokw[t * 2 + 1] = 1.f - w0;
    atomicAdd(&route[i0], 1);
    atomicAdd(&route[i1], 1);
  }
}

__global__ void prefix_kernel(int* route) {
  if (threadIdx.x == 0) {
    int o = 0;
    for (int e = 0; e < 8; e++) { route[16 + e] = o; o += route[e]; }
  }
  if (threadIdx.x < 8) route[8 + threadIdx.x] = 0;
}

__global__ __launch_bounds__(256) void scatter_kernel(
    const int* __restrict__ toke, const float* __restrict__ tokw,
    int* __restrict__ route, int* __restrict__ tokc,
    float* __restrict__ gatew, int* __restrict__ tslots) {
  int t = blockIdx.x * 256 + threadIdx.x;
  if (t >= 4096) return;
  for (int j = 0; j < 2; j++) {
    int e = toke[t * 2 + j];
    int p = atomicAdd(&route[8 + e], 1);
    int slot = route[16 + e] + p;
    tokc[slot] = t;
    gatew[slot] = tokw[t * 2 + j];
    tslots[t * 2 + j] = slot;
  }
}

__global__ __launch_bounds__(256) void moe_act(const float* __restrict__ g,
                                               const float* __restrict__ u,
                                               const float* __restrict__ gatew,
                                               f16* __restrict__ act) {
  int i = blockIdx.x * 256 + threadIdx.x;
  int slot = i >> 10;
  float gv = g[i], uv = u[i];
  float sig = 1.f / (1.f + expf(-gv));
  act[i] = (f16)(gatew[slot] * gv * sig * uv);
}

__global__ __launch_bounds__(256) void final_add(float* __restrict__ outp,
                                                 const float* __restrict__ eo,
                                                 const int* __restrict__ tslots) {
  int i = blockIdx.x * 256 + threadIdx.x;
  int t = i >> 11, d = i & 2047;
  int s0 = tslots[t * 2], s1 = tslots[t * 2 + 1];
  outp[i] += eo[(long)s0 * 2048 + d] + eo[(long)s1 * 2048 + d];
}

// ---------------------------------------------------------------- launcher

extern "C" void kernel_launch(void* const* d_in, const int* in_sizes, int n_in,
                              void* d_out, int out_size, void* d_ws, size_t ws_size,
                              hipStream_t stream) {
  const float* x   = (const float*)d_in[0];
  const float* wan = (const float*)d_in[1];
  const float* wq  = (const float*)d_in[2];
  const float* wk  = (const float*)d_in[3];
  const float* wvp = (const float*)d_in[4];
  const float* wqn = (const float*)d_in[5];
  const float* wkn = (const float*)d_in[6];
  const float* wo  = (const float*)d_in[7];
  const float* wfn = (const float*)d_in[8];
  const float* wr  = (const float*)d_in[9];
  const float* wg  = (const float*)d_in[10];
  const float* wu  = (const float*)d_in[11];
  const float* wd  = (const float*)d_in[12];
  float* out = (float*)d_out;
  char* ws = (char*)d_ws;

  size_t off = 0;
  auto alloc = [&](size_t b) { size_t r = off; off += (b + 255) & ~(size_t)255; return r; };
  size_t o_qf  = alloc((size_t)4096 * 2048 * 4);   // q fp32 | later: gate fp32
  size_t o_kf  = alloc((size_t)4096 * 512 * 4);    // k fp32
  size_t o_vt  = alloc((size_t)4096 * 512 * 4);    // V^T f16 [b][kvh][d][s]
  size_t o_r3  = alloc((size_t)41943040);          // q/k/o f16 | later: up fp32
  size_t o_h   = alloc((size_t)4096 * 2048 * 2);   // h f16 | later: act f16
  size_t o_h2  = alloc((size_t)4096 * 2048 * 2);   // h2 f16
  size_t o_wqh = alloc((size_t)2048 * 2048 * 2);
  size_t o_wkh = alloc((size_t)512 * 2048 * 2);
  size_t o_wvh = alloc((size_t)512 * 2048 * 2);
  size_t o_woh = alloc((size_t)2048 * 2048 * 2);
  size_t o_r10 = alloc((size_t)2 * 8 * 1024 * 2048 * 2);  // wg+wu f16 | later: eo fp32
  size_t o_wdh = alloc((size_t)8 * 2048 * 1024 * 2);
  size_t o_cos = alloc((size_t)2048 * 64 * 4);
  size_t o_sin = alloc((size_t)2048 * 64 * 4);
  size_t o_rt  = alloc(256);
  size_t o_toke = alloc(4096 * 2 * 4);
  size_t o_tokw = alloc(4096 * 2 * 4);
  size_t o_tokc = alloc(4096 * 2 * 4);
  size_t o_gw   = alloc(4096 * 2 * 4);
  size_t o_ts   = alloc(4096 * 2 * 4);
  (void)ws_size; (void)in_sizes; (void)n_in; (void)out_size;

  float* qf = (float*)(ws + o_qf);
  float* gf = qf;
  float* kf = (float*)(ws + o_kf);
  f16* vth = (f16*)(ws + o_vt);
  f16* qh = (f16*)(ws + o_r3);
  f16* kh = (f16*)(ws + o_r3 + 16777216);
  f16* oh = (f16*)(ws + o_r3 + 25165824);
  float* uf = (float*)(ws + o_r3);
  f16* h16 = (f16*)(ws + o_h);
  f16* act16 = (f16*)(ws + o_h);
  f16* h2h = (f16*)(ws + o_h2);
  f16* wqh = (f16*)(ws + o_wqh);
  f16* wkh = (f16*)(ws + o_wkh);
  f16* wvh = (f16*)(ws + o_wvh);
  f16* woh = (f16*)(ws + o_woh);
  f16* wgh = (f16*)(ws + o_r10);
  f16* wuh = (f16*)(ws + o_r10 + 33554432);
  float* eo = (float*)(ws + o_r10);
  f16* wdh = (f16*)(ws + o_wdh);
  float* cost = (float*)(ws + o_cos);
  float* sint = (float*)(ws + o_sin);
  int* route = (int*)(ws + o_rt);
  int* toke = (int*)(ws + o_toke);
  float* tokw = (float*)(ws + o_tokw);
  int* tokc = (int*)(ws + o_tokc);
  float* gatew = (float*)(ws + o_gw);
  int* tslots = (int*)(ws + o_ts);

  // weights -> fp16
  cvt_f16<<<4096, 256, 0, stream>>>(wq, wqh, 1048576);
  cvt_f16<<<1024, 256, 0, stream>>>(wk, wkh, 262144);
  cvt_f16<<<1024, 256, 0, stream>>>(wvp, wvh, 262144);
  cvt_f16<<<4096, 256, 0, stream>>>(wo, woh, 1048576);
  cvt_f16<<<16384, 256, 0, stream>>>(wg, wgh, 4194304);
  cvt_f16<<<16384, 256, 0, stream>>>(wu, wuh, 4194304);
  cvt_f16<<<16384, 256, 0, stream>>>(wd, wdh, 4194304);
  rope_tables<<<512, 256, 0, stream>>>(cost, sint);

  // attention block
  rmsnorm_f16<<<4096, 256, 0, stream>>>(x, wan, h16);
  gemm_nt<<<dim3(32, 16, 1), 256, 0, stream>>>(h16, wqh, qf, nullptr, nullptr, nullptr, nullptr, nullptr, 4096, 2048, 2048, 0);
  gemm_nt<<<dim3(32, 4, 1), 256, 0, stream>>>(h16, wkh, kf, nullptr, nullptr, nullptr, nullptr, nullptr, 4096, 512, 2048, 0);
  gemm_nt<<<dim3(32, 4, 1), 256, 0, stream>>>(h16, wvh, nullptr, nullptr, vth, nullptr, nullptr, nullptr, 4096, 512, 2048, 0);
  qknorm_rope<<<65536, 128, 0, stream>>>(qf, wqn, cost, sint, qh, 16, 0.08838834764831845f);
  qknorm_rope<<<16384, 128, 0, stream>>>(kf, wkn, cost, sint, kh, 4, 1.0f);
  attn_kernel<<<dim3(16, 32, 1), 256, 0, stream>>>(qh, kh, vth, oh);
  gemm_nt<<<dim3(32, 16, 1), 256, 0, stream>>>(oh, woh, out, x, nullptr, nullptr, nullptr, nullptr, 4096, 2048, 2048, 0);

  // MoE block
  rmsnorm_f16<<<4096, 256, 0, stream>>>(out, wfn, h2h);
  zero8<<<1, 64, 0, stream>>>(route);
  router_kernel<<<4096, 256, 0, stream>>>(out, wfn, wr, route, toke, tokw);
  prefix_kernel<<<1, 64, 0, stream>>>(route);
  scatter_kernel<<<16, 256, 0, stream>>>(toke, tokw, route, tokc, gatew, tslots);
  gemm_nt<<<dim3(32, 8, 8), 256, 0, stream>>>(h2h, wgh, gf, nullptr, nullptr, tokc, route + 16, route, 4096, 1024, 2048, 2097152);
  gemm_nt<<<dim3(32, 8, 8), 256, 0, stream>>>(h2h, wuh, uf, nullptr, nullptr, tokc, route + 16, route, 4096, 1024, 2048, 2097152);
  moe_act<<<32768, 256, 0, stream>>>(gf, uf, gatew, act16);
  gemm_nt<<<dim3(32, 16, 8), 256, 0, stream>>>(act16, wdh, eo, nullptr, nullptr, nullptr, route + 16, route, 4096, 2048, 1024, 2097152);
  final_add<<<32768, 256, 0, stream>>>(out, eo, tslots);
}

// Round 3
// 1447.607 us; speedup vs baseline: 1.3116x; 1.2379x over previous
//
#include <hip/hip_runtime.h>

typedef _Float16 f16;
typedef __attribute__((ext_vector_type(8))) _Float16 f16x8;
typedef __attribute__((ext_vector_type(4))) _Float16 f16x4;
typedef __attribute__((ext_vector_type(4))) float f32x4;

// B=2 S=2048 D=2048 H=16 KVH=4 HD=128 E=8 TOPK=2 F=1024, T=B*S=4096

#define GLD_LDS(gp, lp) \
  __builtin_amdgcn_global_load_lds((__attribute__((address_space(1))) void*)(gp), \
                                   (__attribute__((address_space(3))) void*)(lp), 16, 0, 0)

// ---------------------------------------------------------------- utilities

__global__ __launch_bounds__(256) void cvt_f16(const float* __restrict__ in,
                                               f16* __restrict__ outp, int n4) {
  int i = blockIdx.x * 256 + threadIdx.x;
  if (i >= n4) return;
  float4 v = ((const float4*)in)[i];
  f16x4 o;
  o[0] = (f16)v.x; o[1] = (f16)v.y; o[2] = (f16)v.z; o[3] = (f16)v.w;
  ((f16x4*)outp)[i] = o;
}

__global__ __launch_bounds__(256) void rope_tables(float* __restrict__ cost,
                                                   float* __restrict__ sint) {
  int i = blockIdx.x * 256 + threadIdx.x;
  if (i >= 2048 * 64) return;
  int s = i >> 6, j = i & 63;
  float invf = powf(10000.f, -(float)j * (1.f / 64.f));
  float ang = (float)s * invf;
  cost[i] = cosf(ang);
  sint[i] = sinf(ang);
}

// x[t][2048] -> f16 rmsnorm output
__global__ __launch_bounds__(256) void rmsnorm_f16(const float* __restrict__ X,
                                                   const float* __restrict__ w,
                                                   f16* __restrict__ outp) {
  int t = blockIdx.x, tid = threadIdx.x;
  const float* row = X + (long)t * 2048;
  float4 v0 = ((const float4*)row)[tid];
  float4 v1 = ((const float4*)row)[tid + 256];
  float ss = v0.x * v0.x + v0.y * v0.y + v0.z * v0.z + v0.w * v0.w +
             v1.x * v1.x + v1.y * v1.y + v1.z * v1.z + v1.w * v1.w;
  for (int o = 32; o; o >>= 1) ss += __shfl_xor(ss, o);
  __shared__ float red[4];
  if ((tid & 63) == 0) red[tid >> 6] = ss;
  __syncthreads();
  ss = red[0] + red[1] + red[2] + red[3];
  float inv = rsqrtf(ss * (1.f / 2048.f) + 1e-6f);
  float4 w0 = ((const float4*)w)[tid];
  float4 w1 = ((const float4*)w)[tid + 256];
  f16x4 a, b;
  a[0] = (f16)(v0.x * inv * w0.x); a[1] = (f16)(v0.y * inv * w0.y);
  a[2] = (f16)(v0.z * inv * w0.z); a[3] = (f16)(v0.w * inv * w0.w);
  b[0] = (f16)(v1.x * inv * w1.x); b[1] = (f16)(v1.y * inv * w1.y);
  b[2] = (f16)(v1.z * inv * w1.z); b[3] = (f16)(v1.w * inv * w1.w);
  f16x4* orow = (f16x4*)(outp + (long)t * 2048);
  orow[tid] = a;
  orow[tid + 256] = b;
}

// ---------------------------------------------------------------- NT GEMM
// C[row][n] = sum_k A[arow][k] * W[n][k]  (+Res), MFMA 16x16x32 f16.
// 128x128 tile, 4 waves each 64x64 (4x4 MFMA tiles), BK=32, m97-style
// global_load_lds staging. Ct non-null: write f16 transposed [b*N+col][2048].
__global__ __launch_bounds__(256) void gemm_nt(
    const f16* __restrict__ A, const f16* __restrict__ W0,
    float* __restrict__ C, const float* __restrict__ Res, f16* __restrict__ Ct,
    const int* __restrict__ gather, const int* __restrict__ eoff,
    const int* __restrict__ ecnt, int M, int N, int K, long wstride) {
  int e = blockIdx.z;
  int row0 = 0, nrows = M;
  if (eoff) { row0 = eoff[e]; nrows = ecnt[e]; }
  int mt = blockIdx.x;
  if (mt * 128 >= nrows) return;
  int nt = blockIdx.y;
  const f16* W = W0 + (long)e * wstride;

  __shared__ __align__(16) f16 As[128 * 32];
  __shared__ __align__(16) f16 Bs[128 * 32];

  int tid = threadIdx.x;
  int lane = tid & 63, wid = tid >> 6;
  int quad = lane >> 4, l15 = lane & 15;
  int wm = wid & 1, wn = wid >> 1;

  long arow[2]; int brow[2]; int rowi[2];
  for (int r = 0; r < 2; r++) {
    rowi[r] = r * 64 + (tid >> 2);
    int lr = mt * 128 + rowi[r];
    int g = (lr < nrows) ? (row0 + lr) : row0;
    arow[r] = gather ? gather[g] : g;
    brow[r] = nt * 128 + rowi[r];
  }
  int kc8 = (tid & 3) * 8;

  f32x4 acc[4][4] = {};
  for (int k0 = 0; k0 < K; k0 += 32) {
    __syncthreads();
    for (int r = 0; r < 2; r++) {
      GLD_LDS(A + arow[r] * K + k0 + kc8, &As[rowi[r] * 32 + kc8]);
      GLD_LDS(W + (long)brow[r] * K + k0 + kc8, &Bs[rowi[r] * 32 + kc8]);
    }
    __syncthreads();
    f16x8 a[4], b[4];
    for (int i = 0; i < 4; i++)
      a[i] = *(const f16x8*)&As[(wm * 64 + i * 16 + l15) * 32 + quad * 8];
    for (int j = 0; j < 4; j++)
      b[j] = *(const f16x8*)&Bs[(wn * 64 + j * 16 + l15) * 32 + quad * 8];
    for (int i = 0; i < 4; i++)
      for (int j = 0; j < 4; j++)
        acc[i][j] = __builtin_amdgcn_mfma_f32_16x16x32_f16(a[i], b[j], acc[i][j], 0, 0, 0);
  }
  // epilogue: C/D layout row=(lane>>4)*4+reg, col=lane&15  [m89/m91 verified]
  for (int i = 0; i < 4; i++) {
    int lrb = mt * 128 + wm * 64 + i * 16 + quad * 4;
    for (int rr = 0; rr < 4; rr++) {
      int lr = lrb + rr;
      if (lr >= nrows) continue;
      long orow = row0 + lr;
      if (Ct) {  // transposed f16 out: [b][col][s], b=orow>>11 s=orow&2047
        int bb = (int)(orow >> 11), s2 = (int)(orow & 2047);
        for (int j = 0; j < 4; j++) {
          int col = nt * 128 + wn * 64 + j * 16 + l15;
          Ct[((long)(bb * N + col)) * 2048 + s2] = (f16)acc[i][j][rr];
        }
      } else {
        for (int j = 0; j < 4; j++) {
          int col = nt * 128 + wn * 64 + j * 16 + l15;
          float v = acc[i][j][rr];
          if (Res) v += Res[orow * N + col];
          C[orow * N + col] = v;
        }
      }
    }
  }
}

// ------------------------------------------------- q/k per-head norm + rope
// one block per token; each wave handles heads wv, wv+4, ...
// lane holds the RoPE pair (d, d+64) -> no LDS, one wave-reduce per head.
__global__ __launch_bounds__(256) void qknorm_rope(
    const float* __restrict__ X, const float* __restrict__ wn,
    const float* __restrict__ cost, const float* __restrict__ sint,
    f16* __restrict__ outp, int nh, float scale) {
  int t = blockIdx.x;
  int b = t >> 11, s = t & 2047;
  int wv = threadIdx.x >> 6, ln = threadIdx.x & 63;
  float c = cost[s * 64 + ln], sn = sint[s * 64 + ln];
  float w1 = wn[ln], w2 = wn[ln + 64];
  for (int h = wv; h < nh; h += 4) {
    const float* row = X + ((long)t * nh + h) * 128;
    float x1 = row[ln], x2 = row[ln + 64];
    float ss = x1 * x1 + x2 * x2;
    for (int o = 32; o; o >>= 1) ss += __shfl_xor(ss, o);
    float inv = rsqrtf(ss * (1.f / 128.f) + 1e-6f);
    float n1 = x1 * inv * w1, n2 = x2 * inv * w2;
    f16* orow = outp + ((long)(b * nh + h) * 2048 + s) * 128;
    orow[ln] = (f16)((n1 * c - n2 * sn) * scale);
    orow[ln + 64] = (f16)((n1 * sn + n2 * c) * scale);
  }
}

// ---------------------------------------------------------- flash attention
// Q pre-scaled by 1/sqrt(HD). BQ=64 (4 waves x 16 q-rows), BK=64.
// Causal fold: block jj handles q-tiles jj and 31-jj -> 33 K-tiles each
// (perfect balance). Fixed-shift softmax p=exp(s-5): no running max, no
// rescale, no per-iter shuffles (li sums the f16-rounded p for consistency).
// K: [b][kvh][s][128] f16. V: TRANSPOSED [b][kvh][d][s] f16 (from V-GEMM).
__global__ __launch_bounds__(256, 3) void attn_kernel(
    const f16* __restrict__ Q, const f16* __restrict__ Kb,
    const f16* __restrict__ Vtg, f16* __restrict__ O) {
  int jj = blockIdx.x;
  int bh = blockIdx.y;
  int b = bh >> 4, h = bh & 15;
  int kvh = h >> 2;
  int tid = threadIdx.x, lane = tid & 63, wid = tid >> 6;
  int quad = lane >> 4, l15 = lane & 15;

  const f16* Kg = Kb + (long)(b * 4 + kvh) * 2048 * 128;
  const f16* Vg = Vtg + (long)(b * 4 + kvh) * 128 * 2048;

  const int KSTR = 136, VSTR = 72, PSTR = 72;
  __shared__ __align__(16) f16 Ks[64 * 136];
  __shared__ __align__(16) f16 Vs[128 * 72];
  __shared__ __align__(16) f16 Ps[4][16 * 72];

  int krow[4], kc[4], vd[4], vc[4];
  for (int c2 = 0; c2 < 4; c2++) {
    int idx = c2 * 256 + tid;
    krow[c2] = idx >> 4; kc[c2] = (idx & 15) * 8;
    vd[c2] = idx >> 3;  vc[c2] = (idx & 7) * 8;
  }

  for (int ph = 0; ph < 2; ph++) {
    int qt = ph ? (31 - jj) : jj;
    int q0 = qt * 64;
    int rowb = q0 + wid * 16 + quad * 4;

    const f16* Qb = Q + ((long)(b * 16 + h) * 2048 + q0 + wid * 16) * 128;
    f16x8 qfr[4];
    for (int c = 0; c < 4; c++)
      qfr[c] = *(const f16x8*)(Qb + (long)l15 * 128 + c * 32 + quad * 8);

    f32x4 oacc[8] = {};
    float li[4] = {0.f, 0.f, 0.f, 0.f};

    f16x8 kpre[4], vpre[4];
    for (int c2 = 0; c2 < 4; c2++) {
      kpre[c2] = *(const f16x8*)(Kg + (long)krow[c2] * 128 + kc[c2]);
      vpre[c2] = *(const f16x8*)(Vg + (long)vd[c2] * 2048 + vc[c2]);
    }

    for (int kt = 0; kt <= qt; kt++) {
      int k0 = kt * 64;
      __syncthreads();
      for (int c2 = 0; c2 < 4; c2++) {
        *(f16x8*)&Ks[krow[c2] * KSTR + kc[c2]] = kpre[c2];
        *(f16x8*)&Vs[vd[c2] * VSTR + vc[c2]] = vpre[c2];
      }
      if (kt < qt) {
        int k1 = (kt + 1) * 64;
        for (int c2 = 0; c2 < 4; c2++) {
          kpre[c2] = *(const f16x8*)(Kg + (long)(k1 + krow[c2]) * 128 + kc[c2]);
          vpre[c2] = *(const f16x8*)(Vg + (long)vd[c2] * 2048 + k1 + vc[c2]);
        }
      }
      __syncthreads();
      f32x4 sc[4] = {};
      for (int hf = 0; hf < 4; hf++)
        for (int c = 0; c < 4; c++) {
          f16x8 kf = *(const f16x8*)&Ks[(hf * 16 + l15) * KSTR + c * 32 + quad * 8];
          sc[hf] = __builtin_amdgcn_mfma_f32_16x16x32_f16(qfr[c], kf, sc[hf], 0, 0, 0);
        }
      bool dg = (kt == qt);
      for (int r = 0; r < 4; r++) {
        int row = rowb + r;
        float acc = 0.f;
        for (int hf = 0; hf < 4; hf++) {
          float pv = exp2f(sc[hf][r] * 1.44269504f - 7.21347520f);
          if (dg && (k0 + hf * 16 + l15 > row)) pv = 0.f;
          f16 phh = (f16)pv;
          Ps[wid][(quad * 4 + r) * PSTR + hf * 16 + l15] = phh;
          acc += (float)phh;
        }
        li[r] += acc;
      }
      for (int c = 0; c < 2; c++) {
        f16x8 pa = *(const f16x8*)&Ps[wid][l15 * PSTR + c * 32 + quad * 8];
        for (int n = 0; n < 8; n++) {
          f16x8 vf = *(const f16x8*)&Vs[(n * 16 + l15) * VSTR + c * 32 + quad * 8];
          oacc[n] = __builtin_amdgcn_mfma_f32_16x16x32_f16(pa, vf, oacc[n], 0, 0, 0);
        }
      }
    }
    for (int r = 0; r < 4; r++) {
      float s = li[r];
      for (int o = 8; o; o >>= 1) s += __shfl_xor(s, o);
      float inv = 1.f / s;
      int row = rowb + r;
      long basep = ((long)(b * 2048 + row)) * 2048 + h * 128;
      for (int n = 0; n < 8; n++)
        O[basep + n * 16 + l15] = (f16)(oacc[n][r] * inv);
    }
  }
}

// ---------------------------------------------------------------- routing
__global__ void zero8(int* p) { if (threadIdx.x < 8) p[threadIdx.x] = 0; }

__global__ __launch_bounds__(256) void router_kernel(
    const float* __restrict__ X2, const float* __restrict__ wfn,
    const float* __restrict__ wr, int* __restrict__ route,
    int* __restrict__ toke, float* __restrict__ tokw) {
  int t = blockIdx.x, tid = threadIdx.x;
  const float* row = X2 + (long)t * 2048;
  float xv[8];
  float ss = 0.f;
  for (int j = 0; j < 8; j++) {
    float v = row[tid + j * 256];
    xv[j] = v;
    ss += v * v;
  }
  for (int o = 32; o; o >>= 1) ss += __shfl_xor(ss, o);
  __shared__ float red[4];
  int lane = tid & 63, wid = tid >> 6;
  if (lane == 0) red[wid] = ss;
  __syncthreads();
  ss = red[0] + red[1] + red[2] + red[3];
  float inv = rsqrtf(ss * (1.f / 2048.f) + 1e-6f);
  float xw[8];
  for (int j = 0; j < 8; j++) xw[j] = xv[j] * wfn[tid + j * 256];
  float lg[8];
  for (int e = 0; e < 8; e++) {
    float a = 0.f;
    for (int j = 0; j < 8; j++) a += xw[j] * wr[e * 2048 + tid + j * 256];
    for (int o = 32; o; o >>= 1) a += __shfl_xor(a, o);
    lg[e] = a;
  }
  __shared__ float lred[4][8];
  if (lane == 0)
    for (int e = 0; e < 8; e++) lred[wid][e] = lg[e];
  __syncthreads();
  if (tid == 0) {
    float l[8];
    for (int e = 0; e < 8; e++)
      l[e] = (lred[0][e] + lred[1][e] + lred[2][e] + lred[3][e]) * inv;
    int i0 = 0; float b0 = l[0];
    for (int e = 1; e < 8; e++) if (l[e] > b0) { b0 = l[e]; i0 = e; }
    int i1 = -1; float b1 = -__builtin_inff();
    for (int e = 0; e < 8; e++) {
      if (e == i0) continue;
      if (l[e] > b1) { b1 = l[e]; i1 = e; }
    }
    float w0 = 1.f / (1.f + expf(b1 - b0));
    toke[t * 2] = i0; toke[t * 2 + 1] = i1;
    tokw[t * 2] = w0; tokw[t * 2 + 1] = 1.f - w0;
    atomicAdd(&route[i0], 1);
    atomicAdd(&route[i1], 1);
  }
}

__global__ void prefix_kernel(int* route) {
  if (threadIdx.x == 0) {
    int o = 0;
    for (int e = 0; e < 8; e++) { route[16 + e] = o; o += route[e]; }
  }
  if (threadIdx.x < 8) route[8 + threadIdx.x] = 0;
}

__global__ __launch_bounds__(256) void scatter_kernel(
    const int* __restrict__ toke, const float* __restrict__ tokw,
    int* __restrict__ route, int* __restrict__ tokc,
    float* __restrict__ gatew, int* __restrict__ tslots) {
  int t = blockIdx.x * 256 + threadIdx.x;
  if (t >= 4096) return;
  for (int j = 0; j < 2; j++) {
    int e = toke[t * 2 + j];
    int p = atomicAdd(&route[8 + e], 1);
    int slot = route[16 + e] + p;
    tokc[slot] = t;
    gatew[slot] = tokw[t * 2 + j];
    tslots[t * 2 + j] = slot;
  }
}

__global__ __launch_bounds__(256) void moe_act(const float* __restrict__ g,
                                               const float* __restrict__ u,
                                               const float* __restrict__ gatew,
                                               f16* __restrict__ act) {
  int i4 = blockIdx.x * 256 + threadIdx.x;  // over 8192*1024/4
  int slot = i4 >> 8;
  float4 g4 = ((const float4*)g)[i4];
  float4 u4 = ((const float4*)u)[i4];
  float gw = gatew[slot];
  f16x4 o;
  o[0] = (f16)(gw * g4.x * u4.x / (1.f + expf(-g4.x)));
  o[1] = (f16)(gw * g4.y * u4.y / (1.f + expf(-g4.y)));
  o[2] = (f16)(gw * g4.z * u4.z / (1.f + expf(-g4.z)));
  o[3] = (f16)(gw * g4.w * u4.w / (1.f + expf(-g4.w)));
  ((f16x4*)act)[i4] = o;
}

__global__ __launch_bounds__(256) void final_add(float* __restrict__ outp,
                                                 const float* __restrict__ eo,
                                                 const int* __restrict__ tslots) {
  int i4 = blockIdx.x * 256 + threadIdx.x;  // over 4096*2048/4
  int t = i4 >> 9, d4 = i4 & 511;
  int s0 = tslots[t * 2], s1 = tslots[t * 2 + 1];
  float4 a = ((const float4*)outp)[i4];
  float4 e0 = ((const float4*)eo)[(long)s0 * 512 + d4];
  float4 e1 = ((const float4*)eo)[(long)s1 * 512 + d4];
  a.x += e0.x + e1.x; a.y += e0.y + e1.y;
  a.z += e0.z + e1.z; a.w += e0.w + e1.w;
  ((float4*)outp)[i4] = a;
}

// ---------------------------------------------------------------- launcher

extern "C" void kernel_launch(void* const* d_in, const int* in_sizes, int n_in,
                              void* d_out, int out_size, void* d_ws, size_t ws_size,
                              hipStream_t stream) {
  const float* x   = (const float*)d_in[0];
  const float* wan = (const float*)d_in[1];
  const float* wq  = (const float*)d_in[2];
  const float* wk  = (const float*)d_in[3];
  const float* wvp = (const float*)d_in[4];
  const float* wqn = (const float*)d_in[5];
  const float* wkn = (const float*)d_in[6];
  const float* wo  = (const float*)d_in[7];
  const float* wfn = (const float*)d_in[8];
  const float* wr  = (const float*)d_in[9];
  const float* wg  = (const float*)d_in[10];
  const float* wu  = (const float*)d_in[11];
  const float* wd  = (const float*)d_in[12];
  float* out = (float*)d_out;
  char* ws = (char*)d_ws;

  size_t off = 0;
  auto alloc = [&](size_t b) { size_t r = off; off += (b + 255) & ~(size_t)255; return r; };
  size_t o_qf  = alloc((size_t)4096 * 2048 * 4);   // q fp32 | later: gate fp32
  size_t o_kf  = alloc((size_t)4096 * 512 * 4);    // k fp32
  size_t o_vt  = alloc((size_t)4096 * 512 * 4);    // V^T f16 [b][kvh][d][s]
  size_t o_r3  = alloc((size_t)41943040);          // q/k/o f16 | later: up fp32
  size_t o_h   = alloc((size_t)4096 * 2048 * 2);   // h f16 | later: act f16
  size_t o_h2  = alloc((size_t)4096 * 2048 * 2);   // h2 f16
  size_t o_wqh = alloc((size_t)2048 * 2048 * 2);
  size_t o_wkh = alloc((size_t)512 * 2048 * 2);
  size_t o_wvh = alloc((size_t)512 * 2048 * 2);
  size_t o_woh = alloc((size_t)2048 * 2048 * 2);
  size_t o_r10 = alloc((size_t)2 * 8 * 1024 * 2048 * 2);  // wg+wu f16 | later: eo fp32
  size_t o_wdh = alloc((size_t)8 * 2048 * 1024 * 2);
  size_t o_cos = alloc((size_t)2048 * 64 * 4);
  size_t o_sin = alloc((size_t)2048 * 64 * 4);
  size_t o_rt  = alloc(256);
  size_t o_toke = alloc(4096 * 2 * 4);
  size_t o_tokw = alloc(4096 * 2 * 4);
  size_t o_tokc = alloc(4096 * 2 * 4);
  size_t o_gw   = alloc(4096 * 2 * 4);
  size_t o_ts   = alloc(4096 * 2 * 4);
  (void)ws_size; (void)in_sizes; (void)n_in; (void)out_size;

  float* qf = (float*)(ws + o_qf);
  float* gf = qf;
  float* kf = (float*)(ws + o_kf);
  f16* vth = (f16*)(ws + o_vt);
  f16* qh = (f16*)(ws + o_r3);
  f16* kh = (f16*)(ws + o_r3 + 16777216);
  f16* oh = (f16*)(ws + o_r3 + 25165824);
  float* uf = (float*)(ws + o_r3);
  f16* h16 = (f16*)(ws + o_h);
  f16* act16 = (f16*)(ws + o_h);
  f16* h2h = (f16*)(ws + o_h2);
  f16* wqh = (f16*)(ws + o_wqh);
  f16* wkh = (f16*)(ws + o_wkh);
  f16* wvh = (f16*)(ws + o_wvh);
  f16* woh = (f16*)(ws + o_woh);
  f16* wgh = (f16*)(ws + o_r10);
  f16* wuh = (f16*)(ws + o_r10 + 33554432);
  float* eo = (float*)(ws + o_r10);
  f16* wdh = (f16*)(ws + o_wdh);
  float* cost = (float*)(ws + o_cos);
  float* sint = (float*)(ws + o_sin);
  int* route = (int*)(ws + o_rt);
  int* toke = (int*)(ws + o_toke);
  float* tokw = (float*)(ws + o_tokw);
  int* tokc = (int*)(ws + o_tokc);
  float* gatew = (float*)(ws + o_gw);
  int* tslots = (int*)(ws + o_ts);

  // weights -> fp16
  cvt_f16<<<4096, 256, 0, stream>>>(wq, wqh, 1048576);
  cvt_f16<<<1024, 256, 0, stream>>>(wk, wkh, 262144);
  cvt_f16<<<1024, 256, 0, stream>>>(wvp, wvh, 262144);
  cvt_f16<<<4096, 256, 0, stream>>>(wo, woh, 1048576);
  cvt_f16<<<16384, 256, 0, stream>>>(wg, wgh, 4194304);
  cvt_f16<<<16384, 256, 0, stream>>>(wu, wuh, 4194304);
  cvt_f16<<<16384, 256, 0, stream>>>(wd, wdh, 4194304);
  rope_tables<<<512, 256, 0, stream>>>(cost, sint);

  // attention block
  rmsnorm_f16<<<4096, 256, 0, stream>>>(x, wan, h16);
  gemm_nt<<<dim3(32, 16, 1), 256, 0, stream>>>(h16, wqh, qf, nullptr, nullptr, nullptr, nullptr, nullptr, 4096, 2048, 2048, 0);
  gemm_nt<<<dim3(32, 4, 1), 256, 0, stream>>>(h16, wkh, kf, nullptr, nullptr, nullptr, nullptr, nullptr, 4096, 512, 2048, 0);
  gemm_nt<<<dim3(32, 4, 1), 256, 0, stream>>>(h16, wvh, nullptr, nullptr, vth, nullptr, nullptr, nullptr, 4096, 512, 2048, 0);
  qknorm_rope<<<4096, 256, 0, stream>>>(qf, wqn, cost, sint, qh, 16, 0.08838834764831845f);
  qknorm_rope<<<4096, 256, 0, stream>>>(kf, wkn, cost, sint, kh, 4, 1.0f);
  attn_kernel<<<dim3(16, 32, 1), 256, 0, stream>>>(qh, kh, vth, oh);
  gemm_nt<<<dim3(32, 16, 1), 256, 0, stream>>>(oh, woh, out, x, nullptr, nullptr, nullptr, nullptr, 4096, 2048, 2048, 0);

  // MoE block
  rmsnorm_f16<<<4096, 256, 0, stream>>>(out, wfn, h2h);
  zero8<<<1, 64, 0, stream>>>(route);
  router_kernel<<<4096, 256, 0, stream>>>(out, wfn, wr, route, toke, tokw);
  prefix_kernel<<<1, 64, 0, stream>>>(route);
  scatter_kernel<<<16, 256, 0, stream>>>(toke, tokw, route, tokc, gatew, tslots);
  gemm_nt<<<dim3(32, 8, 8), 256, 0, stream>>>(h2h, wgh, gf, nullptr, nullptr, tokc, route + 16, route, 4096, 1024, 2048, 2097152);
  gemm_nt<<<dim3(32, 8, 8), 256, 0, stream>>>(h2h, wuh, uf, nullptr, nullptr, tokc, route + 16, route, 4096, 1024, 2048, 2097152);
  moe_act<<<8192, 256, 0, stream>>>(gf, uf, gatew, act16);
  gemm_nt<<<dim3(32, 16, 8), 256, 0, stream>>>(act16, wdh, eo, nullptr, nullptr, nullptr, route + 16, route, 4096, 2048, 1024, 2097152);
  final_add<<<8192, 256, 0, stream>>>(out, eo, tslots);
}

// Round 4
// 1094.315 us; speedup vs baseline: 1.7351x; 1.3228x over previous
//
#include <hip/hip_runtime.h>

typedef _Float16 f16;
typedef __attribute__((ext_vector_type(8))) _Float16 f16x8;
typedef __attribute__((ext_vector_type(4))) _Float16 f16x4;
typedef __attribute__((ext_vector_type(4))) float f32x4;

// B=2 S=2048 D=2048 H=16 KVH=4 HD=128 E=8 TOPK=2 F=1024, T=B*S=4096

#define GLD_LDS(gp, lp) \
  __builtin_amdgcn_global_load_lds((__attribute__((address_space(1))) void*)(gp), \
                                   (__attribute__((address_space(3))) void*)(lp), 16, 0, 0)

// ---------------------------------------------------------------- utilities

__global__ __launch_bounds__(256) void cvt_f16(const float* __restrict__ in,
                                               f16* __restrict__ outp, int n4) {
  int i = blockIdx.x * 256 + threadIdx.x;
  if (i >= n4) return;
  float4 v = ((const float4*)in)[i];
  f16x4 o;
  o[0] = (f16)v.x; o[1] = (f16)v.y; o[2] = (f16)v.z; o[3] = (f16)v.w;
  ((f16x4*)outp)[i] = o;
}

// wg/wu [e][1024][2048] fp32 -> wguh [e][2048][2048] f16 (gate rows 0-1023, up 1024-2047)
__global__ __launch_bounds__(256) void cvt_gu(const float* __restrict__ in,
                                              f16* __restrict__ outp, int up) {
  int i4 = blockIdx.x * 256 + threadIdx.x;  // < 4194304
  int e = i4 >> 19;                          // 524288 float4 per expert-half
  float4 v = ((const float4*)in)[i4];
  f16x4 o;
  o[0] = (f16)v.x; o[1] = (f16)v.y; o[2] = (f16)v.z; o[3] = (f16)v.w;
  ((f16x4*)outp)[i4 + (long)(e + up) * 524288] = o;
}

__global__ __launch_bounds__(256) void rope_tables(float* __restrict__ cost,
                                                   float* __restrict__ sint) {
  int i = blockIdx.x * 256 + threadIdx.x;
  if (i >= 2048 * 64) return;
  int s = i >> 6, j = i & 63;
  float invf = powf(10000.f, -(float)j * (1.f / 64.f));
  float ang = (float)s * invf;
  cost[i] = cosf(ang);
  sint[i] = sinf(ang);
}

// x[t][2048] fp32 -> f16 rmsnorm output
__global__ __launch_bounds__(256) void rmsnorm_f16(const float* __restrict__ X,
                                                   const float* __restrict__ w,
                                                   f16* __restrict__ outp) {
  int t = blockIdx.x, tid = threadIdx.x;
  const float* row = X + (long)t * 2048;
  float4 v0 = ((const float4*)row)[tid];
  float4 v1 = ((const float4*)row)[tid + 256];
  float ss = v0.x * v0.x + v0.y * v0.y + v0.z * v0.z + v0.w * v0.w +
             v1.x * v1.x + v1.y * v1.y + v1.z * v1.z + v1.w * v1.w;
  for (int o = 32; o; o >>= 1) ss += __shfl_xor(ss, o);
  __shared__ float red[4];
  if ((tid & 63) == 0) red[tid >> 6] = ss;
  __syncthreads();
  ss = red[0] + red[1] + red[2] + red[3];
  float inv = rsqrtf(ss * (1.f / 2048.f) + 1e-6f);
  float4 w0 = ((const float4*)w)[tid];
  float4 w1 = ((const float4*)w)[tid + 256];
  f16x4 a, b;
  a[0] = (f16)(v0.x * inv * w0.x); a[1] = (f16)(v0.y * inv * w0.y);
  a[2] = (f16)(v0.z * inv * w0.z); a[3] = (f16)(v0.w * inv * w0.w);
  b[0] = (f16)(v1.x * inv * w1.x); b[1] = (f16)(v1.y * inv * w1.y);
  b[2] = (f16)(v1.z * inv * w1.z); b[3] = (f16)(v1.w * inv * w1.w);
  f16x4* orow = (f16x4*)(outp + (long)t * 2048);
  orow[tid] = a;
  orow[tid + 256] = b;
}

// ---------------------------------------------------------------- NT GEMM
// C[row][n] = sum_k A[arow][k] * W[n][k], MFMA 16x16x32 f16.
// 128x128 tile, 4 waves (2x2), 4x4 MFMA tiles each, BK=64.
// Staging via global_load_lds w=16 with XOR chunk-swizzle (chunk^=row&7 on the
// GLOBAL side so LDS dest stays wave-uniform+lane*16; frag ds_read_b128 lands
// 2-way on banks = free). Epilogue modes: C fp32 (+Res) | Ct f16 transposed
// [b][col][s] | Ch f16 rows.
__global__ __launch_bounds__(256) void gemm_nt(
    const f16* __restrict__ A, const f16* __restrict__ W0,
    float* __restrict__ C, const float* __restrict__ Res, f16* __restrict__ Ct,
    f16* __restrict__ Ch,
    const int* __restrict__ gather, const int* __restrict__ eoff,
    const int* __restrict__ ecnt, int M, int N, int K, long wstride) {
  int e = blockIdx.z;
  int row0 = 0, nrows = M;
  if (eoff) { row0 = eoff[e]; nrows = ecnt[e]; }
  int mt = blockIdx.x;
  if (mt * 128 >= nrows) return;
  int nt = blockIdx.y;
  const f16* W = W0 + (long)e * wstride;

  __shared__ __align__(16) f16 As[128 * 64];
  __shared__ __align__(16) f16 Bs[128 * 64];

  int tid = threadIdx.x;
  int lane = tid & 63, wid = tid >> 6;
  int quad = lane >> 4, l15 = lane & 15;
  int wm = wid & 1, wn = wid >> 1;

  // staging: 4 insts each; inst r covers rows r*32 + (tid>>3), chunk tid&7
  int srow = tid >> 3, ssub = tid & 7;
  long arowK[4], browK[4];
  for (int r = 0; r < 4; r++) {
    int rw = r * 32 + srow;
    int lr = mt * 128 + rw;
    int g = (lr < nrows) ? (row0 + lr) : row0;
    arowK[r] = (long)(gather ? gather[g] : g) * K;
    browK[r] = (long)(nt * 128 + rw) * K;
  }
  int gcol = ((ssub ^ (srow & 7)) * 8);  // swizzled source column (f16 elems)

  f32x4 acc[4][4] = {};
  for (int k0 = 0; k0 < K; k0 += 64) {
    __syncthreads();
    for (int r = 0; r < 4; r++) {
      GLD_LDS(A + arowK[r] + k0 + gcol, &As[(r * 256 + tid) * 8]);
      GLD_LDS(W + browK[r] + k0 + gcol, &Bs[(r * 256 + tid) * 8]);
    }
    __syncthreads();
    for (int c = 0; c < 2; c++) {
      f16x8 av[4], bv[4];
      for (int i = 0; i < 4; i++) {
        int row = wm * 64 + i * 16 + l15;
        av[i] = *(const f16x8*)&As[row * 64 + (((c * 4 + quad) ^ (row & 7)) * 8)];
      }
      for (int j = 0; j < 4; j++) {
        int row = wn * 64 + j * 16 + l15;
        bv[j] = *(const f16x8*)&Bs[row * 64 + (((c * 4 + quad) ^ (row & 7)) * 8)];
      }
      for (int i = 0; i < 4; i++)
        for (int j = 0; j < 4; j++)
          acc[i][j] = __builtin_amdgcn_mfma_f32_16x16x32_f16(av[i], bv[j], acc[i][j], 0, 0, 0);
    }
  }
  // epilogue: C/D layout row=(lane>>4)*4+reg, col=lane&15  [m89/m91 verified]
  for (int i = 0; i < 4; i++) {
    int lrb = mt * 128 + wm * 64 + i * 16 + quad * 4;
    for (int rr = 0; rr < 4; rr++) {
      int lr = lrb + rr;
      if (lr >= nrows) continue;
      long orow = row0 + lr;
      if (Ct) {  // transposed f16: [b][col][s], b=orow>>11 s=orow&2047
        int bb = (int)(orow >> 11), s2 = (int)(orow & 2047);
        for (int j = 0; j < 4; j++) {
          int col = nt * 128 + wn * 64 + j * 16 + l15;
          Ct[((long)(bb * N + col)) * 2048 + s2] = (f16)acc[i][j][rr];
        }
      } else if (Ch) {  // f16 rows
        for (int j = 0; j < 4; j++) {
          int col = nt * 128 + wn * 64 + j * 16 + l15;
          Ch[orow * N + col] = (f16)acc[i][j][rr];
        }
      } else {
        for (int j = 0; j < 4; j++) {
          int col = nt * 128 + wn * 64 + j * 16 + l15;
          float v = acc[i][j][rr];
          if (Res) v += Res[orow * N + col];
          C[orow * N + col] = v;
        }
      }
    }
  }
}

// ------------------------------------------------- q/k per-head norm + rope
// one block per token; lane holds the RoPE pair (d, d+64) -> no LDS.
__global__ __launch_bounds__(256) void qknorm_rope(
    const f16* __restrict__ X, const float* __restrict__ wn,
    const float* __restrict__ cost, const float* __restrict__ sint,
    f16* __restrict__ outp, int nh, float scale) {
  int t = blockIdx.x;
  int b = t >> 11, s = t & 2047;
  int wv = threadIdx.x >> 6, ln = threadIdx.x & 63;
  float c = cost[s * 64 + ln], sn = sint[s * 64 + ln];
  float w1 = wn[ln], w2 = wn[ln + 64];
  for (int h = wv; h < nh; h += 4) {
    const f16* row = X + ((long)t * nh + h) * 128;
    float x1 = (float)row[ln], x2 = (float)row[ln + 64];
    float ss = x1 * x1 + x2 * x2;
    for (int o = 32; o; o >>= 1) ss += __shfl_xor(ss, o);
    float inv = rsqrtf(ss * (1.f / 128.f) + 1e-6f);
    float n1 = x1 * inv * w1, n2 = x2 * inv * w2;
    f16* orow = outp + ((long)(b * nh + h) * 2048 + s) * 128;
    orow[ln] = (f16)((n1 * c - n2 * sn) * scale);
    orow[ln + 64] = (f16)((n1 * sn + n2 * c) * scale);
  }
}

// ---------------------------------------------------------- flash attention
// Q pre-scaled by 1/sqrt(HD). BQ=64 (4 waves x 16 q-rows), BK=64.
// Causal fold: block jj handles q-tiles jj and 31-jj -> 33 K-tiles each.
// Fixed-shift softmax p=exp(s-5): no running max / rescale.
__global__ __launch_bounds__(256, 3) void attn_kernel(
    const f16* __restrict__ Q, const f16* __restrict__ Kb,
    const f16* __restrict__ Vtg, f16* __restrict__ O) {
  int jj = blockIdx.x;
  int bh = blockIdx.y;
  int b = bh >> 4, h = bh & 15;
  int kvh = h >> 2;
  int tid = threadIdx.x, lane = tid & 63, wid = tid >> 6;
  int quad = lane >> 4, l15 = lane & 15;

  const f16* Kg = Kb + (long)(b * 4 + kvh) * 2048 * 128;
  const f16* Vg = Vtg + (long)(b * 4 + kvh) * 128 * 2048;

  const int KSTR = 136, VSTR = 72, PSTR = 72;
  __shared__ __align__(16) f16 Ks[64 * 136];
  __shared__ __align__(16) f16 Vs[128 * 72];
  __shared__ __align__(16) f16 Ps[4][16 * 72];

  int krow[4], kc[4], vd[4], vc[4];
  for (int c2 = 0; c2 < 4; c2++) {
    int idx = c2 * 256 + tid;
    krow[c2] = idx >> 4; kc[c2] = (idx & 15) * 8;
    vd[c2] = idx >> 3;  vc[c2] = (idx & 7) * 8;
  }

  for (int ph = 0; ph < 2; ph++) {
    int qt = ph ? (31 - jj) : jj;
    int q0 = qt * 64;
    int rowb = q0 + wid * 16 + quad * 4;

    const f16* Qb = Q + ((long)(b * 16 + h) * 2048 + q0 + wid * 16) * 128;
    f16x8 qfr[4];
    for (int c = 0; c < 4; c++)
      qfr[c] = *(const f16x8*)(Qb + (long)l15 * 128 + c * 32 + quad * 8);

    f32x4 oacc[8] = {};
    float li[4] = {0.f, 0.f, 0.f, 0.f};

    f16x8 kpre[4], vpre[4];
    for (int c2 = 0; c2 < 4; c2++) {
      kpre[c2] = *(const f16x8*)(Kg + (long)krow[c2] * 128 + kc[c2]);
      vpre[c2] = *(const f16x8*)(Vg + (long)vd[c2] * 2048 + vc[c2]);
    }

    for (int kt = 0; kt <= qt; kt++) {
      int k0 = kt * 64;
      __syncthreads();
      for (int c2 = 0; c2 < 4; c2++) {
        *(f16x8*)&Ks[krow[c2] * KSTR + kc[c2]] = kpre[c2];
        *(f16x8*)&Vs[vd[c2] * VSTR + vc[c2]] = vpre[c2];
      }
      if (kt < qt) {
        int k1 = (kt + 1) * 64;
        for (int c2 = 0; c2 < 4; c2++) {
          kpre[c2] = *(const f16x8*)(Kg + (long)(k1 + krow[c2]) * 128 + kc[c2]);
          vpre[c2] = *(const f16x8*)(Vg + (long)vd[c2] * 2048 + k1 + vc[c2]);
        }
      }
      __syncthreads();
      f32x4 sc[4] = {};
      for (int hf = 0; hf < 4; hf++)
        for (int c = 0; c < 4; c++) {
          f16x8 kf = *(const f16x8*)&Ks[(hf * 16 + l15) * KSTR + c * 32 + quad * 8];
          sc[hf] = __builtin_amdgcn_mfma_f32_16x16x32_f16(qfr[c], kf, sc[hf], 0, 0, 0);
        }
      bool dg = (kt == qt);
      for (int r = 0; r < 4; r++) {
        int row = rowb + r;
        float acc = 0.f;
        for (int hf = 0; hf < 4; hf++) {
          float pv = exp2f(sc[hf][r] * 1.44269504f - 7.21347520f);
          if (dg && (k0 + hf * 16 + l15 > row)) pv = 0.f;
          f16 phh = (f16)pv;
          Ps[wid][(quad * 4 + r) * PSTR + hf * 16 + l15] = phh;
          acc += (float)phh;
        }
        li[r] += acc;
      }
      for (int c = 0; c < 2; c++) {
        f16x8 pa = *(const f16x8*)&Ps[wid][l15 * PSTR + c * 32 + quad * 8];
        for (int n = 0; n < 8; n++) {
          f16x8 vf = *(const f16x8*)&Vs[(n * 16 + l15) * VSTR + c * 32 + quad * 8];
          oacc[n] = __builtin_amdgcn_mfma_f32_16x16x32_f16(pa, vf, oacc[n], 0, 0, 0);
        }
      }
    }
    for (int r = 0; r < 4; r++) {
      float s = li[r];
      for (int o = 8; o; o >>= 1) s += __shfl_xor(s, o);
      float inv = 1.f / s;
      int row = rowb + r;
      long basep = ((long)(b * 2048 + row)) * 2048 + h * 128;
      for (int n = 0; n < 8; n++)
        O[basep + n * 16 + l15] = (f16)(oacc[n][r] * inv);
    }
  }
}

// ---------------------------------------------------------------- routing
__global__ void zero8(int* p) { if (threadIdx.x < 8) p[threadIdx.x] = 0; }

__global__ __launch_bounds__(256) void router_kernel(
    const float* __restrict__ X2, const float* __restrict__ wfn,
    const float* __restrict__ wr, int* __restrict__ route,
    int* __restrict__ toke, float* __restrict__ tokw) {
  int t = blockIdx.x, tid = threadIdx.x;
  const float* row = X2 + (long)t * 2048;
  float xv[8];
  float ss = 0.f;
  for (int j = 0; j < 8; j++) {
    float v = row[tid + j * 256];
    xv[j] = v;
    ss += v * v;
  }
  for (int o = 32; o; o >>= 1) ss += __shfl_xor(ss, o);
  __shared__ float red[4];
  int lane = tid & 63, wid = tid >> 6;
  if (lane == 0) red[wid] = ss;
  __syncthreads();
  ss = red[0] + red[1] + red[2] + red[3];
  float inv = rsqrtf(ss * (1.f / 2048.f) + 1e-6f);
  float xw[8];
  for (int j = 0; j < 8; j++) xw[j] = xv[j] * wfn[tid + j * 256];
  float lg[8];
  for (int e = 0; e < 8; e++) {
    float a = 0.f;
    for (int j = 0; j < 8; j++) a += xw[j] * wr[e * 2048 + tid + j * 256];
    for (int o = 32; o; o >>= 1) a += __shfl_xor(a, o);
    lg[e] = a;
  }
  __shared__ float lred[4][8];
  if (lane == 0)
    for (int e = 0; e < 8; e++) lred[wid][e] = lg[e];
  __syncthreads();
  if (tid == 0) {
    float l[8];
    for (int e = 0; e < 8; e++)
      l[e] = (lred[0][e] + lred[1][e] + lred[2][e] + lred[3][e]) * inv;
    int i0 = 0; float b0 = l[0];
    for (int e = 1; e < 8; e++) if (l[e] > b0) { b0 = l[e]; i0 = e; }
    int i1 = -1; float b1 = -__builtin_inff();
    for (int e = 0; e < 8; e++) {
      if (e == i0) continue;
      if (l[e] > b1) { b1 = l[e]; i1 = e; }
    }
    float w0 = 1.f / (1.f + expf(b1 - b0));
    toke[t * 2] = i0; toke[t * 2 + 1] = i1;
    tokw[t * 2] = w0; tokw[t * 2 + 1] = 1.f - w0;
    atomicAdd(&route[i0], 1);
    atomicAdd(&route[i1], 1);
  }
}

__global__ void prefix_kernel(int* route) {
  if (threadIdx.x == 0) {
    int o = 0;
    for (int e = 0; e < 8; e++) { route[16 + e] = o; o += route[e]; }
  }
  if (threadIdx.x < 8) route[8 + threadIdx.x] = 0;
}

__global__ __launch_bounds__(256) void scatter_kernel(
    const int* __restrict__ toke, const float* __restrict__ tokw,
    int* __restrict__ route, int* __restrict__ tokc,
    float* __restrict__ gatew, int* __restrict__ tslots) {
  int t = blockIdx.x * 256 + threadIdx.x;
  if (t >= 4096) return;
  for (int j = 0; j < 2; j++) {
    int e = toke[t * 2 + j];
    int p = atomicAdd(&route[8 + e], 1);
    int slot = route[16 + e] + p;
    tokc[slot] = t;
    gatew[slot] = tokw[t * 2 + j];
    tslots[t * 2 + j] = slot;
  }
}

// gu: [slot][2048] f16 (gate 0..1023, up 1024..2047) -> act f16 [slot][1024]
__global__ __launch_bounds__(256) void moe_act(const f16* __restrict__ gu,
                                               const float* __restrict__ gatew,
                                               f16* __restrict__ act) {
  int i8 = blockIdx.x * 256 + threadIdx.x;  // over 8192*1024/8
  int slot = i8 >> 7, f8 = (i8 & 127) * 8;
  const f16* rowp = gu + (long)slot * 2048;
  f16x8 g8 = *(const f16x8*)(rowp + f8);
  f16x8 u8 = *(const f16x8*)(rowp + 1024 + f8);
  float gw = gatew[slot];
  f16x8 o;
  for (int j = 0; j < 8; j++) {
    float g = (float)g8[j], u = (float)u8[j];
    o[j] = (f16)(gw * g * u / (1.f + expf(-g)));
  }
  *(f16x8*)(act + (long)slot * 1024 + f8) = o;
}

// out += eo[slot0] + eo[slot1]   (eo f16 [slot][2048])
__global__ __launch_bounds__(256) void final_add(float* __restrict__ outp,
                                                 const f16* __restrict__ eo,
                                                 const int* __restrict__ tslots) {
  int i4 = blockIdx.x * 256 + threadIdx.x;  // over 4096*2048/4
  int t = i4 >> 9, d4 = (i4 & 511) * 4;
  int s0 = tslots[t * 2], s1 = tslots[t * 2 + 1];
  float4 a = ((const float4*)outp)[i4];
  f16x4 e0 = *(const f16x4*)(eo + (long)s0 * 2048 + d4);
  f16x4 e1 = *(const f16x4*)(eo + (long)s1 * 2048 + d4);
  a.x += (float)e0[0] + (float)e1[0];
  a.y += (float)e0[1] + (float)e1[1];
  a.z += (float)e0[2] + (float)e1[2];
  a.w += (float)e0[3] + (float)e1[3];
  ((float4*)outp)[i4] = a;
}

// ---------------------------------------------------------------- launcher

extern "C" void kernel_launch(void* const* d_in, const int* in_sizes, int n_in,
                              void* d_out, int out_size, void* d_ws, size_t ws_size,
                              hipStream_t stream) {
  const float* x   = (const float*)d_in[0];
  const float* wan = (const float*)d_in[1];
  const float* wq  = (const float*)d_in[2];
  const float* wk  = (const float*)d_in[3];
  const float* wvp = (const float*)d_in[4];
  const float* wqn = (const float*)d_in[5];
  const float* wkn = (const float*)d_in[6];
  const float* wo  = (const float*)d_in[7];
  const float* wfn = (const float*)d_in[8];
  const float* wr  = (const float*)d_in[9];
  const float* wg  = (const float*)d_in[10];
  const float* wu  = (const float*)d_in[11];
  const float* wd  = (const float*)d_in[12];
  float* out = (float*)d_out;
  char* ws = (char*)d_ws;

  size_t off = 0;
  auto alloc = [&](size_t b) { size_t r = off; off += (b + 255) & ~(size_t)255; return r; };
  // region lifetimes annotated (total ~210 MB)
  size_t o_RA  = alloc((size_t)16 * 1024 * 1024);  // h16 | oh | act16
  size_t o_RB  = alloc((size_t)16 * 1024 * 1024);  // qpre f16 | h2h
  size_t o_RC  = alloc((size_t)16 * 1024 * 1024);  // qh (post-rope)
  size_t o_kp  = alloc((size_t)4 * 1024 * 1024);   // kpre f16 [t][512]
  size_t o_kh  = alloc((size_t)4 * 1024 * 1024);   // kh post-rope
  size_t o_vt  = alloc((size_t)4 * 1024 * 1024);   // V^T f16 [b][kvh][d][s]
  size_t o_gf  = alloc((size_t)32 * 1024 * 1024);  // gate+up f16 [slot][2048] | eo f16
  size_t o_wqh = alloc((size_t)2048 * 2048 * 2);
  size_t o_wkh = alloc((size_t)512 * 2048 * 2);
  size_t o_wvh = alloc((size_t)512 * 2048 * 2);
  size_t o_woh = alloc((size_t)2048 * 2048 * 2);
  size_t o_wgu = alloc((size_t)8 * 2048 * 2048 * 2);  // fused [e][2048][2048]
  size_t o_wdh = alloc((size_t)8 * 2048 * 1024 * 2);
  size_t o_cos = alloc((size_t)2048 * 64 * 4);
  size_t o_sin = alloc((size_t)2048 * 64 * 4);
  size_t o_rt  = alloc(256);
  size_t o_toke = alloc(4096 * 2 * 4);
  size_t o_tokw = alloc(4096 * 2 * 4);
  size_t o_tokc = alloc(4096 * 2 * 4);
  size_t o_gw   = alloc(4096 * 2 * 4);
  size_t o_ts   = alloc(4096 * 2 * 4);
  (void)ws_size; (void)in_sizes; (void)n_in; (void)out_size;

  f16* h16   = (f16*)(ws + o_RA);
  f16* oh    = (f16*)(ws + o_RA);
  f16* act16 = (f16*)(ws + o_RA);
  f16* qpre  = (f16*)(ws + o_RB);
  f16* h2h   = (f16*)(ws + o_RB);
  f16* qh    = (f16*)(ws + o_RC);
  f16* kpre  = (f16*)(ws + o_kp);
  f16* kh    = (f16*)(ws + o_kh);
  f16* vth   = (f16*)(ws + o_vt);
  f16* gf16  = (f16*)(ws + o_gf);
  f16* eo16  = (f16*)(ws + o_gf);
  f16* wqh = (f16*)(ws + o_wqh);
  f16* wkh = (f16*)(ws + o_wkh);
  f16* wvh = (f16*)(ws + o_wvh);
  f16* woh = (f16*)(ws + o_woh);
  f16* wguh = (f16*)(ws + o_wgu);
  f16* wdh = (f16*)(ws + o_wdh);
  float* cost = (float*)(ws + o_cos);
  float* sint = (float*)(ws + o_sin);
  int* route = (int*)(ws + o_rt);
  int* toke = (int*)(ws + o_toke);
  float* tokw = (float*)(ws + o_tokw);
  int* tokc = (int*)(ws + o_tokc);
  float* gatew = (float*)(ws + o_gw);
  int* tslots = (int*)(ws + o_ts);

  // weights -> fp16
  cvt_f16<<<4096, 256, 0, stream>>>(wq, wqh, 1048576);
  cvt_f16<<<1024, 256, 0, stream>>>(wk, wkh, 262144);
  cvt_f16<<<1024, 256, 0, stream>>>(wvp, wvh, 262144);
  cvt_f16<<<4096, 256, 0, stream>>>(wo, woh, 1048576);
  cvt_gu<<<16384, 256, 0, stream>>>(wg, wguh, 0);
  cvt_gu<<<16384, 256, 0, stream>>>(wu, wguh, 1);
  cvt_f16<<<16384, 256, 0, stream>>>(wd, wdh, 4194304);
  rope_tables<<<512, 256, 0, stream>>>(cost, sint);

  // attention block
  rmsnorm_f16<<<4096, 256, 0, stream>>>(x, wan, h16);
  gemm_nt<<<dim3(32, 16, 1), 256, 0, stream>>>(h16, wqh, nullptr, nullptr, nullptr, qpre, nullptr, nullptr, nullptr, 4096, 2048, 2048, 0);
  gemm_nt<<<dim3(32, 4, 1), 256, 0, stream>>>(h16, wkh, nullptr, nullptr, nullptr, kpre, nullptr, nullptr, nullptr, 4096, 512, 2048, 0);
  gemm_nt<<<dim3(32, 4, 1), 256, 0, stream>>>(h16, wvh, nullptr, nullptr, vth, nullptr, nullptr, nullptr, nullptr, 4096, 512, 2048, 0);
  qknorm_rope<<<4096, 256, 0, stream>>>(qpre, wqn, cost, sint, qh, 16, 0.08838834764831845f);
  qknorm_rope<<<4096, 256, 0, stream>>>(kpre, wkn, cost, sint, kh, 4, 1.0f);
  attn_kernel<<<dim3(16, 32, 1), 256, 0, stream>>>(qh, kh, vth, oh);
  gemm_nt<<<dim3(32, 16, 1), 256, 0, stream>>>(oh, woh, out, x, nullptr, nullptr, nullptr, nullptr, nullptr, 4096, 2048, 2048, 0);

  // MoE block
  rmsnorm_f16<<<4096, 256, 0, stream>>>(out, wfn, h2h);
  zero8<<<1, 64, 0, stream>>>(route);
  router_kernel<<<4096, 256, 0, stream>>>(out, wfn, wr, route, toke, tokw);
  prefix_kernel<<<1, 64, 0, stream>>>(route);
  scatter_kernel<<<16, 256, 0, stream>>>(toke, tokw, route, tokc, gatew, tslots);
  gemm_nt<<<dim3(16, 16, 8), 256, 0, stream>>>(h2h, wguh, nullptr, nullptr, nullptr, gf16, tokc, route + 16, route, 4096, 2048, 2048, 4194304);
  moe_act<<<4096, 256, 0, stream>>>(gf16, gatew, act16);
  gemm_nt<<<dim3(16, 16, 8), 256, 0, stream>>>(act16, wdh, nullptr, nullptr, nullptr, eo16, nullptr, route + 16, route, 4096, 2048, 1024, 2097152);
  final_add<<<8192, 256, 0, stream>>>(out, eo16, tslots);
}

// Round 5
// 994.298 us; speedup vs baseline: 1.9096x; 1.1006x over previous
//
#include <hip/hip_runtime.h>

typedef _Float16 f16;
typedef __attribute__((ext_vector_type(8))) _Float16 f16x8;
typedef __attribute__((ext_vector_type(4))) _Float16 f16x4;
typedef __attribute__((ext_vector_type(4))) float f32x4;

// B=2 S=2048 D=2048 H=16 KVH=4 HD=128 E=8 TOPK=2 F=1024, T=B*S=4096

#define GLD_LDS(gp, lp) \
  __builtin_amdgcn_global_load_lds((__attribute__((address_space(1))) void*)(gp), \
                                   (__attribute__((address_space(3))) void*)(lp), 16, 0, 0)

// ---------------------------------------------------------------- utilities

__global__ __launch_bounds__(256) void cvt_f16(const float* __restrict__ in,
                                               f16* __restrict__ outp, int n4) {
  int i = blockIdx.x * 256 + threadIdx.x;
  if (i >= n4) return;
  float4 v = ((const float4*)in)[i];
  f16x4 o;
  o[0] = (f16)v.x; o[1] = (f16)v.y; o[2] = (f16)v.z; o[3] = (f16)v.w;
  ((f16x4*)outp)[i] = o;
}

// wg/wu [e][1024][2048] fp32 -> wguh [e][2048][2048] f16 (gate rows 0-1023, up 1024-2047)
__global__ __launch_bounds__(256) void cvt_gu(const float* __restrict__ in,
                                              f16* __restrict__ outp, int up) {
  int i4 = blockIdx.x * 256 + threadIdx.x;  // < 4194304
  int e = i4 >> 19;                          // 524288 float4 per expert-half
  float4 v = ((const float4*)in)[i4];
  f16x4 o;
  o[0] = (f16)v.x; o[1] = (f16)v.y; o[2] = (f16)v.z; o[3] = (f16)v.w;
  ((f16x4*)outp)[i4 + (long)(e + up) * 524288] = o;
}

__global__ __launch_bounds__(256) void rope_tables(float* __restrict__ cost,
                                                   float* __restrict__ sint) {
  int i = blockIdx.x * 256 + threadIdx.x;
  if (i >= 2048 * 64) return;
  int s = i >> 6, j = i & 63;
  float invf = powf(10000.f, -(float)j * (1.f / 64.f));
  float ang = (float)s * invf;
  cost[i] = cosf(ang);
  sint[i] = sinf(ang);
}

// x[t][2048] fp32 -> f16 rmsnorm output
__global__ __launch_bounds__(256) void rmsnorm_f16(const float* __restrict__ X,
                                                   const float* __restrict__ w,
                                                   f16* __restrict__ outp) {
  int t = blockIdx.x, tid = threadIdx.x;
  const float* row = X + (long)t * 2048;
  float4 v0 = ((const float4*)row)[tid];
  float4 v1 = ((const float4*)row)[tid + 256];
  float ss = v0.x * v0.x + v0.y * v0.y + v0.z * v0.z + v0.w * v0.w +
             v1.x * v1.x + v1.y * v1.y + v1.z * v1.z + v1.w * v1.w;
  for (int o = 32; o; o >>= 1) ss += __shfl_xor(ss, o);
  __shared__ float red[4];
  if ((tid & 63) == 0) red[tid >> 6] = ss;
  __syncthreads();
  ss = red[0] + red[1] + red[2] + red[3];
  float inv = rsqrtf(ss * (1.f / 2048.f) + 1e-6f);
  float4 w0 = ((const float4*)w)[tid];
  float4 w1 = ((const float4*)w)[tid + 256];
  f16x4 a, b;
  a[0] = (f16)(v0.x * inv * w0.x); a[1] = (f16)(v0.y * inv * w0.y);
  a[2] = (f16)(v0.z * inv * w0.z); a[3] = (f16)(v0.w * inv * w0.w);
  b[0] = (f16)(v1.x * inv * w1.x); b[1] = (f16)(v1.y * inv * w1.y);
  b[2] = (f16)(v1.z * inv * w1.z); b[3] = (f16)(v1.w * inv * w1.w);
  f16x4* orow = (f16x4*)(outp + (long)t * 2048);
  orow[tid] = a;
  orow[tid + 256] = b;
}

// ---------------------------------------------------------------- NT GEMM
// C[row][n] = sum_k A[arow][k] * W[n][k], MFMA 16x16x32 f16, 128x128 tile,
// 4 waves (2x2), BK=64, gld_lds w=16 staging with XOR chunk-swizzle.
// XCD-contiguous tile swizzle: flat block index, residue-mod-8 classes get
// contiguous mt-major chunks -> same-XCD blocks share W panels in L2.
// Epilogues: qkv 3-way split | Ct f16 transposed | Ch f16 rows | C fp32 (+Res).
__global__ __launch_bounds__(256) void gemm_nt(
    const f16* __restrict__ A, const f16* __restrict__ W0,
    float* __restrict__ C, const float* __restrict__ Res, f16* __restrict__ Ct,
    f16* __restrict__ Ch,
    f16* __restrict__ Cq, f16* __restrict__ Ck, f16* __restrict__ Cv,
    const int* __restrict__ gather, const int* __restrict__ eoff,
    const int* __restrict__ ecnt, int M, int N, int K, long wstride) {
  int e = blockIdx.z;
  int row0 = 0, nrows = M;
  if (eoff) { row0 = eoff[e]; nrows = ecnt[e]; }
  // swizzle: per-XCD contiguous tile chunks (valid when total tiles % 8 == 0)
  int gx = gridDim.x;
  int T = gx * gridDim.y;
  int lin = blockIdx.x + blockIdx.y * gx;
  if ((T & 7) == 0) lin = (lin & 7) * (T >> 3) + (lin >> 3);
  int mt = lin % gx, nt = lin / gx;
  if (mt * 128 >= nrows) return;
  const f16* W = W0 + (long)e * wstride;

  __shared__ __align__(16) f16 As[128 * 64];
  __shared__ __align__(16) f16 Bs[128 * 64];

  int tid = threadIdx.x;
  int lane = tid & 63, wid = tid >> 6;
  int quad = lane >> 4, l15 = lane & 15;
  int wm = wid & 1, wn = wid >> 1;

  // staging: 4 insts each; inst r covers rows r*32 + (tid>>3), chunk tid&7
  int srow = tid >> 3, ssub = tid & 7;
  long arowK[4], browK[4];
  for (int r = 0; r < 4; r++) {
    int rw = r * 32 + srow;
    int lr = mt * 128 + rw;
    int g = (lr < nrows) ? (row0 + lr) : row0;
    arowK[r] = (long)(gather ? gather[g] : g) * K;
    browK[r] = (long)(nt * 128 + rw) * K;
  }
  int gcol = ((ssub ^ (srow & 7)) * 8);  // swizzled source column (f16 elems)

  f32x4 acc[4][4] = {};
  for (int k0 = 0; k0 < K; k0 += 64) {
    __syncthreads();
    for (int r = 0; r < 4; r++) {
      GLD_LDS(A + arowK[r] + k0 + gcol, &As[(r * 256 + tid) * 8]);
      GLD_LDS(W + browK[r] + k0 + gcol, &Bs[(r * 256 + tid) * 8]);
    }
    __syncthreads();
    for (int c = 0; c < 2; c++) {
      f16x8 av[4], bv[4];
      for (int i = 0; i < 4; i++) {
        int row = wm * 64 + i * 16 + l15;
        av[i] = *(const f16x8*)&As[row * 64 + (((c * 4 + quad) ^ (row & 7)) * 8)];
      }
      for (int j = 0; j < 4; j++) {
        int row = wn * 64 + j * 16 + l15;
        bv[j] = *(const f16x8*)&Bs[row * 64 + (((c * 4 + quad) ^ (row & 7)) * 8)];
      }
      for (int i = 0; i < 4; i++)
        for (int j = 0; j < 4; j++)
          acc[i][j] = __builtin_amdgcn_mfma_f32_16x16x32_f16(av[i], bv[j], acc[i][j], 0, 0, 0);
    }
  }
  // epilogue: C/D layout row=(lane>>4)*4+reg, col=lane&15  [m89/m91 verified]
  for (int i = 0; i < 4; i++) {
    int lrb = mt * 128 + wm * 64 + i * 16 + quad * 4;
    for (int rr = 0; rr < 4; rr++) {
      int lr = lrb + rr;
      if (lr >= nrows) continue;
      long orow = row0 + lr;
      if (Cq) {  // fused qkv: cols [0,2048)=q rows, [2048,2560)=k rows, rest V^T
        int bb = (int)(orow >> 11), s2 = (int)(orow & 2047);
        for (int j = 0; j < 4; j++) {
          int col = nt * 128 + wn * 64 + j * 16 + l15;
          f16 v = (f16)acc[i][j][rr];
          if (col < 2048) Cq[orow * 2048 + col] = v;
          else if (col < 2560) Ck[orow * 512 + (col - 2048)] = v;
          else {
            int cc = col - 2560;
            int kv = cc >> 7, d = cc & 127;
            Cv[((long)((bb * 4 + kv) * 128 + d)) * 2048 + s2] = v;
          }
        }
      } else if (Ct) {  // transposed f16: [b][col][s]
        int bb = (int)(orow >> 11), s2 = (int)(orow & 2047);
        for (int j = 0; j < 4; j++) {
          int col = nt * 128 + wn * 64 + j * 16 + l15;
          Ct[((long)(bb * N + col)) * 2048 + s2] = (f16)acc[i][j][rr];
        }
      } else if (Ch) {  // f16 rows
        for (int j = 0; j < 4; j++) {
          int col = nt * 128 + wn * 64 + j * 16 + l15;
          Ch[orow * N + col] = (f16)acc[i][j][rr];
        }
      } else {
        for (int j = 0; j < 4; j++) {
          int col = nt * 128 + wn * 64 + j * 16 + l15;
          float v = acc[i][j][rr];
          if (Res) v += Res[orow * N + col];
          C[orow * N + col] = v;
        }
      }
    }
  }
}

// ------------------------------------------------- q/k per-head norm + rope
// one block per token; lane holds the RoPE pair (d, d+64) -> no LDS.
__global__ __launch_bounds__(256) void qknorm_rope(
    const f16* __restrict__ X, const float* __restrict__ wn,
    const float* __restrict__ cost, const float* __restrict__ sint,
    f16* __restrict__ outp, int nh, float scale) {
  int t = blockIdx.x;
  int b = t >> 11, s = t & 2047;
  int wv = threadIdx.x >> 6, ln = threadIdx.x & 63;
  float c = cost[s * 64 + ln], sn = sint[s * 64 + ln];
  float w1 = wn[ln], w2 = wn[ln + 64];
  for (int h = wv; h < nh; h += 4) {
    const f16* row = X + ((long)t * nh + h) * 128;
    float x1 = (float)row[ln], x2 = (float)row[ln + 64];
    float ss = x1 * x1 + x2 * x2;
    for (int o = 32; o; o >>= 1) ss += __shfl_xor(ss, o);
    float inv = rsqrtf(ss * (1.f / 128.f) + 1e-6f);
    float n1 = x1 * inv * w1, n2 = x2 * inv * w2;
    f16* orow = outp + ((long)(b * nh + h) * 2048 + s) * 128;
    orow[ln] = (f16)((n1 * c - n2 * sn) * scale);
    orow[ln + 64] = (f16)((n1 * sn + n2 * c) * scale);
  }
}

// ---------------------------------------------------------- flash attention
// Q pre-scaled by 1/sqrt(HD). BQ=64 (4 waves x 16 q-rows), BK=64.
// Causal fold: block jj handles q-tiles jj and 31-jj -> 33 K-tiles each.
// Fixed-shift softmax p=exp(s-5): no running max / rescale.
__global__ __launch_bounds__(256, 3) void attn_kernel(
    const f16* __restrict__ Q, const f16* __restrict__ Kb,
    const f16* __restrict__ Vtg, f16* __restrict__ O) {
  int jj = blockIdx.x;
  int bh = blockIdx.y;
  int b = bh >> 4, h = bh & 15;
  int kvh = h >> 2;
  int tid = threadIdx.x, lane = tid & 63, wid = tid >> 6;
  int quad = lane >> 4, l15 = lane & 15;

  const f16* Kg = Kb + (long)(b * 4 + kvh) * 2048 * 128;
  const f16* Vg = Vtg + (long)(b * 4 + kvh) * 128 * 2048;

  const int KSTR = 136, VSTR = 72, PSTR = 72;
  __shared__ __align__(16) f16 Ks[64 * 136];
  __shared__ __align__(16) f16 Vs[128 * 72];
  __shared__ __align__(16) f16 Ps[4][16 * 72];

  int krow[4], kc[4], vd[4], vc[4];
  for (int c2 = 0; c2 < 4; c2++) {
    int idx = c2 * 256 + tid;
    krow[c2] = idx >> 4; kc[c2] = (idx & 15) * 8;
    vd[c2] = idx >> 3;  vc[c2] = (idx & 7) * 8;
  }

  for (int ph = 0; ph < 2; ph++) {
    int qt = ph ? (31 - jj) : jj;
    int q0 = qt * 64;
    int rowb = q0 + wid * 16 + quad * 4;

    const f16* Qb = Q + ((long)(b * 16 + h) * 2048 + q0 + wid * 16) * 128;
    f16x8 qfr[4];
    for (int c = 0; c < 4; c++)
      qfr[c] = *(const f16x8*)(Qb + (long)l15 * 128 + c * 32 + quad * 8);

    f32x4 oacc[8] = {};
    float li[4] = {0.f, 0.f, 0.f, 0.f};

    f16x8 kpre[4], vpre[4];
    for (int c2 = 0; c2 < 4; c2++) {
      kpre[c2] = *(const f16x8*)(Kg + (long)krow[c2] * 128 + kc[c2]);
      vpre[c2] = *(const f16x8*)(Vg + (long)vd[c2] * 2048 + vc[c2]);
    }

    for (int kt = 0; kt <= qt; kt++) {
      int k0 = kt * 64;
      __syncthreads();
      for (int c2 = 0; c2 < 4; c2++) {
        *(f16x8*)&Ks[krow[c2] * KSTR + kc[c2]] = kpre[c2];
        *(f16x8*)&Vs[vd[c2] * VSTR + vc[c2]] = vpre[c2];
      }
      if (kt < qt) {
        int k1 = (kt + 1) * 64;
        for (int c2 = 0; c2 < 4; c2++) {
          kpre[c2] = *(const f16x8*)(Kg + (long)(k1 + krow[c2]) * 128 + kc[c2]);
          vpre[c2] = *(const f16x8*)(Vg + (long)vd[c2] * 2048 + k1 + vc[c2]);
        }
      }
      __syncthreads();
      f32x4 sc[4] = {};
      for (int hf = 0; hf < 4; hf++)
        for (int c = 0; c < 4; c++) {
          f16x8 kf = *(const f16x8*)&Ks[(hf * 16 + l15) * KSTR + c * 32 + quad * 8];
          sc[hf] = __builtin_amdgcn_mfma_f32_16x16x32_f16(qfr[c], kf, sc[hf], 0, 0, 0);
        }
      bool dg = (kt == qt);
      for (int r = 0; r < 4; r++) {
        int row = rowb + r;
        float acc = 0.f;
        for (int hf = 0; hf < 4; hf++) {
          float pv = exp2f(sc[hf][r] * 1.44269504f - 7.21347520f);
          if (dg && (k0 + hf * 16 + l15 > row)) pv = 0.f;
          f16 phh = (f16)pv;
          Ps[wid][(quad * 4 + r) * PSTR + hf * 16 + l15] = phh;
          acc += (float)phh;
        }
        li[r] += acc;
      }
      for (int c = 0; c < 2; c++) {
        f16x8 pa = *(const f16x8*)&Ps[wid][l15 * PSTR + c * 32 + quad * 8];
        for (int n = 0; n < 8; n++) {
          f16x8 vf = *(const f16x8*)&Vs[(n * 16 + l15) * VSTR + c * 32 + quad * 8];
          oacc[n] = __builtin_amdgcn_mfma_f32_16x16x32_f16(pa, vf, oacc[n], 0, 0, 0);
        }
      }
    }
    for (int r = 0; r < 4; r++) {
      float s = li[r];
      for (int o = 8; o; o >>= 1) s += __shfl_xor(s, o);
      float inv = 1.f / s;
      int row = rowb + r;
      long basep = ((long)(b * 2048 + row)) * 2048 + h * 128;
      for (int n = 0; n < 8; n++)
        O[basep + n * 16 + l15] = (f16)(oacc[n][r] * inv);
    }
  }
}

// ---------------------------------------------------------------- routing
__global__ void zero8(int* p) { if (threadIdx.x < 8) p[threadIdx.x] = 0; }

__global__ __launch_bounds__(256) void router_kernel(
    const float* __restrict__ X2, const float* __restrict__ wfn,
    const float* __restrict__ wr, int* __restrict__ route,
    int* __restrict__ toke, float* __restrict__ tokw) {
  int t = blockIdx.x, tid = threadIdx.x;
  const float* row = X2 + (long)t * 2048;
  float xv[8];
  float ss = 0.f;
  for (int j = 0; j < 8; j++) {
    float v = row[tid + j * 256];
    xv[j] = v;
    ss += v * v;
  }
  for (int o = 32; o; o >>= 1) ss += __shfl_xor(ss, o);
  __shared__ float red[4];
  int lane = tid & 63, wid = tid >> 6;
  if (lane == 0) red[wid] = ss;
  __syncthreads();
  ss = red[0] + red[1] + red[2] + red[3];
  float inv = rsqrtf(ss * (1.f / 2048.f) + 1e-6f);
  float xw[8];
  for (int j = 0; j < 8; j++) xw[j] = xv[j] * wfn[tid + j * 256];
  float lg[8];
  for (int e = 0; e < 8; e++) {
    float a = 0.f;
    for (int j = 0; j < 8; j++) a += xw[j] * wr[e * 2048 + tid + j * 256];
    for (int o = 32; o; o >>= 1) a += __shfl_xor(a, o);
    lg[e] = a;
  }
  __shared__ float lred[4][8];
  if (lane == 0)
    for (int e = 0; e < 8; e++) lred[wid][e] = lg[e];
  __syncthreads();
  if (tid == 0) {
    float l[8];
    for (int e = 0; e < 8; e++)
      l[e] = (lred[0][e] + lred[1][e] + lred[2][e] + lred[3][e]) * inv;
    int i0 = 0; float b0 = l[0];
    for (int e = 1; e < 8; e++) if (l[e] > b0) { b0 = l[e]; i0 = e; }
    int i1 = -1; float b1 = -__builtin_inff();
    for (int e = 0; e < 8; e++) {
      if (e == i0) continue;
      if (l[e] > b1) { b1 = l[e]; i1 = e; }
    }
    float w0 = 1.f / (1.f + expf(b1 - b0));
    toke[t * 2] = i0; toke[t * 2 + 1] = i1;
    tokw[t * 2] = w0; tokw[t * 2 + 1] = 1.f - w0;
    atomicAdd(&route[i0], 1);
    atomicAdd(&route[i1], 1);
  }
}

__global__ void prefix_kernel(int* route) {
  if (threadIdx.x == 0) {
    int o = 0;
    for (int e = 0; e < 8; e++) { route[16 + e] = o; o += route[e]; }
  }
  if (threadIdx.x < 8) route[8 + threadIdx.x] = 0;
}

__global__ __launch_bounds__(256) void scatter_kernel(
    const int* __restrict__ toke, const float* __restrict__ tokw,
    int* __restrict__ route, int* __restrict__ tokc,
    float* __restrict__ gatew, int* __restrict__ tslots) {
  int t = blockIdx.x * 256 + threadIdx.x;
  if (t >= 4096) return;
  for (int j = 0; j < 2; j++) {
    int e = toke[t * 2 + j];
    int p = atomicAdd(&route[8 + e], 1);
    int slot = route[16 + e] + p;
    tokc[slot] = t;
    gatew[slot] = tokw[t * 2 + j];
    tslots[t * 2 + j] = slot;
  }
}

// gu: [slot][2048] f16 (gate 0..1023, up 1024..2047) -> act f16 [slot][1024]
__global__ __launch_bounds__(256) void moe_act(const f16* __restrict__ gu,
                                               const float* __restrict__ gatew,
                                               f16* __restrict__ act) {
  int i8 = blockIdx.x * 256 + threadIdx.x;  // over 8192*1024/8
  int slot = i8 >> 7, f8 = (i8 & 127) * 8;
  const f16* rowp = gu + (long)slot * 2048;
  f16x8 g8 = *(const f16x8*)(rowp + f8);
  f16x8 u8 = *(const f16x8*)(rowp + 1024 + f8);
  float gw = gatew[slot];
  f16x8 o;
  for (int j = 0; j < 8; j++) {
    float g = (float)g8[j], u = (float)u8[j];
    o[j] = (f16)(gw * g * u / (1.f + expf(-g)));
  }
  *(f16x8*)(act + (long)slot * 1024 + f8) = o;
}

// out += eo[slot0] + eo[slot1]   (eo f16 [slot][2048])
__global__ __launch_bounds__(256) void final_add(float* __restrict__ outp,
                                                 const f16* __restrict__ eo,
                                                 const int* __restrict__ tslots) {
  int i4 = blockIdx.x * 256 + threadIdx.x;  // over 4096*2048/4
  int t = i4 >> 9, d4 = (i4 & 511) * 4;
  int s0 = tslots[t * 2], s1 = tslots[t * 2 + 1];
  float4 a = ((const float4*)outp)[i4];
  f16x4 e0 = *(const f16x4*)(eo + (long)s0 * 2048 + d4);
  f16x4 e1 = *(const f16x4*)(eo + (long)s1 * 2048 + d4);
  a.x += (float)e0[0] + (float)e1[0];
  a.y += (float)e0[1] + (float)e1[1];
  a.z += (float)e0[2] + (float)e1[2];
  a.w += (float)e0[3] + (float)e1[3];
  ((float4*)outp)[i4] = a;
}

// ---------------------------------------------------------------- launcher

extern "C" void kernel_launch(void* const* d_in, const int* in_sizes, int n_in,
                              void* d_out, int out_size, void* d_ws, size_t ws_size,
                              hipStream_t stream) {
  const float* x   = (const float*)d_in[0];
  const float* wan = (const float*)d_in[1];
  const float* wq  = (const float*)d_in[2];
  const float* wk  = (const float*)d_in[3];
  const float* wvp = (const float*)d_in[4];
  const float* wqn = (const float*)d_in[5];
  const float* wkn = (const float*)d_in[6];
  const float* wo  = (const float*)d_in[7];
  const float* wfn = (const float*)d_in[8];
  const float* wr  = (const float*)d_in[9];
  const float* wg  = (const float*)d_in[10];
  const float* wu  = (const float*)d_in[11];
  const float* wd  = (const float*)d_in[12];
  float* out = (float*)d_out;
  char* ws = (char*)d_ws;

  size_t off = 0;
  auto alloc = [&](size_t b) { size_t r = off; off += (b + 255) & ~(size_t)255; return r; };
  size_t o_RA  = alloc((size_t)16 * 1024 * 1024);  // h16 | oh | act16
  size_t o_RB  = alloc((size_t)16 * 1024 * 1024);  // qpre f16 | h2h
  size_t o_RC  = alloc((size_t)16 * 1024 * 1024);  // qh (post-rope)
  size_t o_kp  = alloc((size_t)4 * 1024 * 1024);   // kpre f16 [t][512]
  size_t o_kh  = alloc((size_t)4 * 1024 * 1024);   // kh post-rope
  size_t o_vt  = alloc((size_t)4 * 1024 * 1024);   // V^T f16 [b][kvh][d][s]
  size_t o_gf  = alloc((size_t)32 * 1024 * 1024);  // gate+up f16 [slot][2048] | eo f16
  size_t o_wqkv = alloc((size_t)3072 * 2048 * 2);  // fused qkv weights f16
  size_t o_woh = alloc((size_t)2048 * 2048 * 2);
  size_t o_wgu = alloc((size_t)8 * 2048 * 2048 * 2);  // fused [e][2048][2048]
  size_t o_wdh = alloc((size_t)8 * 2048 * 1024 * 2);
  size_t o_cos = alloc((size_t)2048 * 64 * 4);
  size_t o_sin = alloc((size_t)2048 * 64 * 4);
  size_t o_rt  = alloc(256);
  size_t o_toke = alloc(4096 * 2 * 4);
  size_t o_tokw = alloc(4096 * 2 * 4);
  size_t o_tokc = alloc(4096 * 2 * 4);
  size_t o_gw   = alloc(4096 * 2 * 4);
  size_t o_ts   = alloc(4096 * 2 * 4);
  (void)ws_size; (void)in_sizes; (void)n_in; (void)out_size;

  f16* h16   = (f16*)(ws + o_RA);
  f16* oh    = (f16*)(ws + o_RA);
  f16* act16 = (f16*)(ws + o_RA);
  f16* qpre  = (f16*)(ws + o_RB);
  f16* h2h   = (f16*)(ws + o_RB);
  f16* qh    = (f16*)(ws + o_RC);
  f16* kpre  = (f16*)(ws + o_kp);
  f16* kh    = (f16*)(ws + o_kh);
  f16* vth   = (f16*)(ws + o_vt);
  f16* gf16  = (f16*)(ws + o_gf);
  f16* eo16  = (f16*)(ws + o_gf);
  f16* wqkvh = (f16*)(ws + o_wqkv);
  f16* woh = (f16*)(ws + o_woh);
  f16* wguh = (f16*)(ws + o_wgu);
  f16* wdh = (f16*)(ws + o_wdh);
  float* cost = (float*)(ws + o_cos);
  float* sint = (float*)(ws + o_sin);
  int* route = (int*)(ws + o_rt);
  int* toke = (int*)(ws + o_toke);
  float* tokw = (float*)(ws + o_tokw);
  int* tokc = (int*)(ws + o_tokc);
  float* gatew = (float*)(ws + o_gw);
  int* tslots = (int*)(ws + o_ts);

  // weights -> fp16 (q rows 0-2047, k rows 2048-2559, v rows 2560-3071)
  cvt_f16<<<4096, 256, 0, stream>>>(wq, wqkvh, 1048576);
  cvt_f16<<<1024, 256, 0, stream>>>(wk, wqkvh + (size_t)2048 * 2048, 262144);
  cvt_f16<<<1024, 256, 0, stream>>>(wvp, wqkvh + (size_t)2560 * 2048, 262144);
  cvt_f16<<<4096, 256, 0, stream>>>(wo, woh, 1048576);
  cvt_gu<<<16384, 256, 0, stream>>>(wg, wguh, 0);
  cvt_gu<<<16384, 256, 0, stream>>>(wu, wguh, 1);
  cvt_f16<<<16384, 256, 0, stream>>>(wd, wdh, 4194304);
  rope_tables<<<512, 256, 0, stream>>>(cost, sint);

  // attention block
  rmsnorm_f16<<<4096, 256, 0, stream>>>(x, wan, h16);
  gemm_nt<<<dim3(32, 24, 1), 256, 0, stream>>>(h16, wqkvh, nullptr, nullptr, nullptr, nullptr, qpre, kpre, vth, nullptr, nullptr, nullptr, 4096, 3072, 2048, 0);
  qknorm_rope<<<4096, 256, 0, stream>>>(qpre, wqn, cost, sint, qh, 16, 0.08838834764831845f);
  qknorm_rope<<<4096, 256, 0, stream>>>(kpre, wkn, cost, sint, kh, 4, 1.0f);
  attn_kernel<<<dim3(16, 32, 1), 256, 0, stream>>>(qh, kh, vth, oh);
  gemm_nt<<<dim3(32, 16, 1), 256, 0, stream>>>(oh, woh, out, x, nullptr, nullptr, nullptr, nullptr, nullptr, nullptr, nullptr, nullptr, 4096, 2048, 2048, 0);

  // MoE block
  rmsnorm_f16<<<4096, 256, 0, stream>>>(out, wfn, h2h);
  zero8<<<1, 64, 0, stream>>>(route);
  router_kernel<<<4096, 256, 0, stream>>>(out, wfn, wr, route, toke, tokw);
  prefix_kernel<<<1, 64, 0, stream>>>(route);
  scatter_kernel<<<16, 256, 0, stream>>>(toke, tokw, route, tokc, gatew, tslots);
  gemm_nt<<<dim3(32, 16, 8), 256, 0, stream>>>(h2h, wguh, nullptr, nullptr, nullptr, gf16, nullptr, nullptr, nullptr, tokc, route + 16, route, 4096, 2048, 2048, 4194304);
  moe_act<<<4096, 256, 0, stream>>>(gf16, gatew, act16);
  gemm_nt<<<dim3(32, 16, 8), 256, 0, stream>>>(act16, wdh, nullptr, nullptr, nullptr, eo16, nullptr, nullptr, nullptr, nullptr, route + 16, route, 4096, 2048, 1024, 2097152);
  final_add<<<8192, 256, 0, stream>>>(out, eo16, tslots);
}